// Round 6
// baseline (705.184 us; speedup 1.0000x reference)
//
#include <hip/hip_runtime.h>

// 2-layer GCNConv, N=500K, E=16M, Cin=1, Cout=4, fp32.
//
// Round-10: the sort pass exists only to enable the DPP scan; the scan
// exists only because round-8's unsorted-atomic reduce failed. But
// round-8's counters (4% VALU, 2% HBM, 45% occ) show its failure was
// GRID SHAPE (245x1024, 1 block/CU, 16 dependent atomics/iter), not
// LDS-atomic cost. This round: unsorted LDS-atomic reduces at FINE
// granularity with the proven reduce grid shape (1954x256, 4-5KB LDS,
// 70% occ). Sort and scan deleted. deg comes from a 2048-wide LDS
// histogram added to k_bin2 (+1 free DS atomic/edge), flushed via 1M
// cheap global atomics; tiny k_y computes y = rsqrt(deg+1)*x.
// Pipeline: bin1 -> bin2d -> y -> red1u (1 atomic/edge) -> red2u (4).

#define B1_BLOCKS 512
#define B1_THREADS 1024
#define TILE1 16384
#define B2_THREADS 1024
#define TILE2 16384
#define MAXNB1 256       // coarse buckets (2048 nodes); needs n <= 524288
#define SORT_STAGE 12032 // fallback k_sort LDS staging; fallback C <= this
// fallback (round-5 flat binning) constants
#define FB_BLOCKS 512
#define FB_THREADS 1024
#define FB_PAD 8
#define MAXNBF 2048

// ---------------- DPP segmented-scan helpers (fallback reduces only) -------
template <int CTRL, int RM, int KOLD>
__device__ __forceinline__ void seg_step1(int m, float& a) {
  const int mm = __builtin_amdgcn_update_dpp(KOLD, m, CTRL, RM, 0xf, true);
  const float f = (mm == m) ? 1.0f : 0.0f;
  const float ba = __int_as_float(
      __builtin_amdgcn_update_dpp(0, __float_as_int(a), CTRL, RM, 0xf, true));
  a = fmaf(ba, f, a);
}

template <int CTRL, int RM, int KOLD>
__device__ __forceinline__ void seg_step4(int m, float& gx, float& gy,
                                          float& gz, float& gw) {
  const int mm = __builtin_amdgcn_update_dpp(KOLD, m, CTRL, RM, 0xf, true);
  const float f = (mm == m) ? 1.0f : 0.0f;
  const float bx = __int_as_float(
      __builtin_amdgcn_update_dpp(0, __float_as_int(gx), CTRL, RM, 0xf, true));
  const float by = __int_as_float(
      __builtin_amdgcn_update_dpp(0, __float_as_int(gy), CTRL, RM, 0xf, true));
  const float bz = __int_as_float(
      __builtin_amdgcn_update_dpp(0, __float_as_int(gz), CTRL, RM, 0xf, true));
  const float bw = __int_as_float(
      __builtin_amdgcn_update_dpp(0, __float_as_int(gw), CTRL, RM, 0xf, true));
  gx = fmaf(bx, f, gx);
  gy = fmaf(by, f, gy);
  gz = fmaf(bz, f, gz);
  gw = fmaf(bw, f, gw);
}

__device__ __forceinline__ void seg_scan1(int m, float& a) {
  seg_step1<0x111, 0xf, 0>(m, a);
  seg_step1<0x112, 0xf, 0>(m, a);
  seg_step1<0x114, 0xf, 0>(m, a);
  seg_step1<0x118, 0xf, 0>(m, a);
  seg_step1<0x142, 0xa, -1>(m, a);
  seg_step1<0x143, 0xc, -1>(m, a);
}

__device__ __forceinline__ void seg_scan4(int m, float& gx, float& gy,
                                          float& gz, float& gw) {
  seg_step4<0x111, 0xf, 0>(m, gx, gy, gz, gw);
  seg_step4<0x112, 0xf, 0>(m, gx, gy, gz, gw);
  seg_step4<0x114, 0xf, 0>(m, gx, gy, gz, gw);
  seg_step4<0x118, 0xf, 0>(m, gx, gy, gz, gw);
  seg_step4<0x142, 0xa, -1>(m, gx, gy, gz, gw);
  seg_step4<0x143, 0xc, -1>(m, gx, gy, gz, gw);
}

// ---------------- pass 1: coarse split (LDS-staged, coalesced flush) -------
__global__ __launch_bounds__(B1_THREADS) void k_bin1(
    const int* __restrict__ src, const int* __restrict__ dst, int E,
    int chunk, int nb1, int C1, int* __restrict__ gcur1,
    int* __restrict__ pay1) {
  __shared__ int out[TILE1];
  __shared__ int hist[MAXNB1], toff[MAXNB1], wcur[MAXNB1], gb[MAXNB1];
  __shared__ int sbuf[2][MAXNB1];
  const int tid = threadIdx.x;
  const long long e0 = (long long)blockIdx.x * chunk;
  long long reml = (long long)E - e0;
  const int lim = reml < 0 ? 0 : (reml < chunk ? (int)reml : chunk);
  const int* dch = dst + e0;
  const int* sch = src + e0;

  for (int tb = 0; tb < lim; tb += TILE1) {
    const int tcnt = min(TILE1, lim - tb);
    const int nv = tcnt >> 2;
    for (int j = tid; j < MAXNB1; j += B1_THREADS) hist[j] = 0;
    __syncthreads();

    // phase A: tile histogram of coarse keys
    const int* dt = dch + tb;
    for (int k = tid; k < nv; k += B1_THREADS) {
      int4 d = reinterpret_cast<const int4*>(dt)[k];
      atomicAdd(&hist[d.x >> 11], 1);
      atomicAdd(&hist[d.y >> 11], 1);
      atomicAdd(&hist[d.z >> 11], 1);
      atomicAdd(&hist[d.w >> 11], 1);
    }
    for (int k = (nv << 2) + tid; k < tcnt; k += B1_THREADS)
      atomicAdd(&hist[dt[k] >> 11], 1);
    __syncthreads();

    // phase B: exclusive scan (256-wide) + exact global range reservation
    if (tid < MAXNB1) sbuf[0][tid] = hist[tid];
    __syncthreads();
    int pi = 0;
    for (int dd = 1; dd < MAXNB1; dd <<= 1) {
      if (tid < MAXNB1) {
        int v = sbuf[pi][tid];
        if (tid >= dd) v += sbuf[pi][tid - dd];
        sbuf[pi ^ 1][tid] = v;
      }
      pi ^= 1;
      __syncthreads();
    }
    if (tid < MAXNB1) {
      int c = hist[tid];
      int exc = sbuf[pi][tid] - c;
      toff[tid] = exc;
      wcur[tid] = exc;
      gb[tid] = c ? atomicAdd(&gcur1[tid], c) : 0;
    }
    __syncthreads();

    // phase C: rank + place packed (src<<11 | dst&2047) into LDS out
    const int* st = sch + tb;
    for (int k = tid; k < nv; k += B1_THREADS) {
      int4 d = reinterpret_cast<const int4*>(dt)[k];
      int4 s = reinterpret_cast<const int4*>(st)[k];
      int r0 = atomicAdd(&wcur[d.x >> 11], 1);
      int r1 = atomicAdd(&wcur[d.y >> 11], 1);
      int r2 = atomicAdd(&wcur[d.z >> 11], 1);
      int r3 = atomicAdd(&wcur[d.w >> 11], 1);
      out[r0] = (s.x << 11) | (d.x & 2047);
      out[r1] = (s.y << 11) | (d.y & 2047);
      out[r2] = (s.z << 11) | (d.z & 2047);
      out[r3] = (s.w << 11) | (d.w & 2047);
    }
    for (int k = (nv << 2) + tid; k < tcnt; k += B1_THREADS) {
      int d = dt[k], s = st[k];
      int r = atomicAdd(&wcur[d >> 11], 1);
      out[r] = (s << 11) | (d & 2047);
    }
    __syncthreads();

    // phase D: wave-per-bucket coalesced copy LDS -> global
    const int wv = tid >> 6, lane = tid & 63;
    for (int j = wv; j < nb1; j += 16) {
      const int c = wcur[j] - toff[j];
      if (!c) continue;
      const int gbase = gb[j];
      const long long pbase = (long long)j * C1;
      for (int q = lane; q < c; q += 64) {
        int gi = gbase + q;
        if (gi < C1) pay1[pbase + gi] = out[toff[j] + q];
      }
    }
    __syncthreads();
  }
}

// ---------------- pass 2: fine split + per-node degree histogram -----------
__global__ __launch_bounds__(B2_THREADS) void k_bin2d(
    const int* __restrict__ pay1, const int* __restrict__ gcur1, int C1,
    int C2, int* __restrict__ gcur2, int* __restrict__ pay2,
    int n, int* __restrict__ deg_g) {
  __shared__ int out[TILE2];
  __shared__ int dh[2048];
  __shared__ int hist[8], toff9[9], wcur[8], gb[8];
  const int cb = blockIdx.x >> 1;
  const int half = blockIdx.x & 1;
  const int tid = threadIdx.x;
  const int Lc = min(gcur1[cb], C1);
  int mid = ((Lc >> 1) + 3) & ~3;
  if (mid > Lc) mid = Lc;
  const int h0 = half ? mid : 0;
  const int h1 = half ? Lc : mid;
  const int* seg = pay1 + (long long)cb * C1;

  dh[tid] = 0;
  dh[tid + 1024] = 0;
  __syncthreads();

  for (int tb = h0; tb < h1; tb += TILE2) {
    const int tcnt = min(TILE2, h1 - tb);
    const int nv = tcnt >> 2;
    if (tid < 8) hist[tid] = 0;
    __syncthreads();
    const int* pt = seg + tb;

    // phase A: 8-wide fine histogram + 2048-wide degree histogram
    for (int k = tid; k < nv; k += B2_THREADS) {
      int4 p = reinterpret_cast<const int4*>(pt)[k];
      atomicAdd(&hist[(p.x >> 8) & 7], 1);
      atomicAdd(&hist[(p.y >> 8) & 7], 1);
      atomicAdd(&hist[(p.z >> 8) & 7], 1);
      atomicAdd(&hist[(p.w >> 8) & 7], 1);
      atomicAdd(&dh[p.x & 2047], 1);
      atomicAdd(&dh[p.y & 2047], 1);
      atomicAdd(&dh[p.z & 2047], 1);
      atomicAdd(&dh[p.w & 2047], 1);
    }
    for (int k = (nv << 2) + tid; k < tcnt; k += B2_THREADS) {
      int p = pt[k];
      atomicAdd(&hist[(p >> 8) & 7], 1);
      atomicAdd(&dh[p & 2047], 1);
    }
    __syncthreads();

    if (tid == 0) {
      int run = 0;
      for (int j = 0; j < 8; ++j) { toff9[j] = run; run += hist[j]; }
      toff9[8] = run;
    }
    __syncthreads();
    if (tid < 8) {
      wcur[tid] = toff9[tid];
      gb[tid] = hist[tid] ? atomicAdd(&gcur2[cb * 8 + tid], hist[tid]) : 0;
    }
    __syncthreads();

    for (int k = tid; k < nv; k += B2_THREADS) {
      int4 p = reinterpret_cast<const int4*>(pt)[k];
      out[atomicAdd(&wcur[(p.x >> 8) & 7], 1)] = ((p.x >> 11) << 8) | (p.x & 255);
      out[atomicAdd(&wcur[(p.y >> 8) & 7], 1)] = ((p.y >> 11) << 8) | (p.y & 255);
      out[atomicAdd(&wcur[(p.z >> 8) & 7], 1)] = ((p.z >> 11) << 8) | (p.z & 255);
      out[atomicAdd(&wcur[(p.w >> 8) & 7], 1)] = ((p.w >> 11) << 8) | (p.w & 255);
    }
    for (int k = (nv << 2) + tid; k < tcnt; k += B2_THREADS) {
      int p = pt[k];
      out[atomicAdd(&wcur[(p >> 8) & 7], 1)] = ((p >> 11) << 8) | (p & 255);
    }
    __syncthreads();

    const int total = toff9[8];
    for (int q = tid; q < total; q += B2_THREADS) {
      int j = (q >= toff9[4]) ? 4 : 0;
      j += (q >= toff9[j + 2]) ? 2 : 0;
      j += (q >= toff9[j + 1]) ? 1 : 0;
      int o = gb[j] + (q - toff9[j]);
      if (o < C2) pay2[(long long)(cb * 8 + j) * C2 + o] = out[q];
    }
    __syncthreads();
  }

  // flush degree histogram (both halves contribute)
  const int nbase = cb << 11;
#pragma unroll
  for (int q = 0; q < 2; ++q) {
    const int j = tid + q * 1024;
    const int c = dh[j];
    const int i = nbase + j;
    if (c && i < n) atomicAdd(&deg_g[i], c);
  }
}

// ---------------- tiny pass: y = rsqrt(deg+1) * x --------------------------
__global__ __launch_bounds__(256) void k_y(
    int n, const int* __restrict__ deg_g, const float* __restrict__ x,
    float* __restrict__ y) {
  const int i = blockIdx.x * 256 + threadIdx.x;
  if (i < n) y[i] = rsqrtf((float)(deg_g[i] + 1)) * x[i];
}

// ---------------- layer-1: unsorted fine-bucket reduce (1 atomic/edge) -----
__global__ __launch_bounds__(256) void k_red1u(
    const int* __restrict__ pay2, const int* __restrict__ gcur2, int C2,
    int n, const float* __restrict__ y, const int* __restrict__ deg_g,
    float2* __restrict__ ds) {
  __shared__ float S[256];
  const int b = blockIdx.x, t = threadIdx.x;
  S[t] = 0.0f;
  __syncthreads();
  const int L = min(gcur2[b], C2);
  const int* seg = pay2 + (long long)b * C2;
  for (int k = t; k < L; k += 256) {
    const int p = __builtin_nontemporal_load(seg + k);
    atomicAdd(&S[p & 255], y[p >> 8]);
  }
  __syncthreads();
  const int i = (b << 8) + t;
  if (i < n) {
    const float r = rsqrtf((float)(deg_g[i] + 1));
    ds[i] = make_float2(r, r * (S[t] + y[i]));
  }
}

// ---------------- layer-2: unsorted message reduce (4 atomics/edge) --------
__global__ __launch_bounds__(256) void k_red2u(
    const int* __restrict__ pay2, const int* __restrict__ gcur2, int C2,
    int n, const float2* __restrict__ ds,
    const float* __restrict__ W1, const float* __restrict__ b1,
    const float* __restrict__ W2, const float* __restrict__ b2,
    float4* __restrict__ out) {
  __shared__ float S0[256], S1[256], S2[256], S3[256];
  const int b = blockIdx.x, t = threadIdx.x;
  S0[t] = 0.f; S1[t] = 0.f; S2[t] = 0.f; S3[t] = 0.f;
  __syncthreads();
  const float w10 = W1[0], w11 = W1[1], w12 = W1[2], w13 = W1[3];
  const float c10 = b1[0], c11 = b1[1], c12 = b1[2], c13 = b1[3];
  float w2[16];
#pragma unroll
  for (int k = 0; k < 16; ++k) w2[k] = W2[k];

  const int L = min(gcur2[b], C2);
  const int* seg = pay2 + (long long)b * C2;
  for (int k = t; k < L; k += 256) {
    const int p = __builtin_nontemporal_load(seg + k);
    const int m = p & 255;
    const float2 v = ds[p >> 8];
    const float r = v.x, s = v.y;
    const float h0 = fmaxf(fmaf(s, w10, c10), 0.f);
    const float h1 = fmaxf(fmaf(s, w11, c11), 0.f);
    const float h2 = fmaxf(fmaf(s, w12, c12), 0.f);
    const float h3 = fmaxf(fmaf(s, w13, c13), 0.f);
    atomicAdd(&S0[m], r * (h0 * w2[0] + h1 * w2[4] + h2 * w2[8]  + h3 * w2[12]));
    atomicAdd(&S1[m], r * (h0 * w2[1] + h1 * w2[5] + h2 * w2[9]  + h3 * w2[13]));
    atomicAdd(&S2[m], r * (h0 * w2[2] + h1 * w2[6] + h2 * w2[10] + h3 * w2[14]));
    atomicAdd(&S3[m], r * (h0 * w2[3] + h1 * w2[7] + h2 * w2[11] + h3 * w2[15]));
  }
  __syncthreads();
  const int i = (b << 8) + t;
  if (i < n) {
    const float2 v = ds[i];
    const float r = v.x, s = v.y;
    const float h0 = fmaxf(fmaf(s, w10, c10), 0.f);
    const float h1 = fmaxf(fmaf(s, w11, c11), 0.f);
    const float h2 = fmaxf(fmaf(s, w12, c12), 0.f);
    const float h3 = fmaxf(fmaf(s, w13, c13), 0.f);
    const float sx = r * (h0 * w2[0] + h1 * w2[4] + h2 * w2[8]  + h3 * w2[12]);
    const float sy = r * (h0 * w2[1] + h1 * w2[5] + h2 * w2[9]  + h3 * w2[13]);
    const float sz = r * (h0 * w2[2] + h1 * w2[6] + h2 * w2[10] + h3 * w2[14]);
    const float sw = r * (h0 * w2[3] + h1 * w2[7] + h2 * w2[11] + h3 * w2[15]);
    out[i] = make_float4(b2[0] + r * (S0[t] + sx),
                         b2[1] + r * (S1[t] + sy),
                         b2[2] + r * (S2[t] + sz),
                         b2[3] + r * (S3[t] + sw));
  }
}

// ---------------- fallback flat binning (round-5, proven) ------------------
__global__ __launch_bounds__(FB_THREADS) void k_bin_flat(
    const int* __restrict__ src, const int* __restrict__ dst, int E,
    int chunk, int nbf, int C, int* __restrict__ gcur,
    int* __restrict__ payload) {
  __shared__ int hist[MAXNBF];
  __shared__ int lbase[MAXNBF];
  const int tid = threadIdx.x;
  const long long e0 = (long long)blockIdx.x * chunk;
  long long rem = (long long)E - e0;
  int lim = rem < 0 ? 0 : (rem < chunk ? (int)rem : chunk);
  for (int j = tid; j < nbf; j += FB_THREADS) hist[j] = 0;
  __syncthreads();
  const int* dch = dst + e0;
  const int* sch = src + e0;
  const int nv = lim >> 2;
  for (int k = tid; k < nv; k += FB_THREADS) {
    int4 d = reinterpret_cast<const int4*>(dch)[k];
    atomicAdd(&hist[d.x >> 8], 1);
    atomicAdd(&hist[d.y >> 8], 1);
    atomicAdd(&hist[d.z >> 8], 1);
    atomicAdd(&hist[d.w >> 8], 1);
  }
  for (int k = (nv << 2) + tid; k < lim; k += FB_THREADS)
    atomicAdd(&hist[dch[k] >> 8], 1);
  __syncthreads();
  for (int j = tid; j < nbf; j += FB_THREADS) {
    int c = hist[j];
    lbase[j] = c ? atomicAdd(&gcur[j], (c + FB_PAD - 1) & ~(FB_PAD - 1)) : 0;
    hist[j] = 0;
  }
  __syncthreads();
  for (int k = tid; k < nv; k += FB_THREADS) {
    int4 d = reinterpret_cast<const int4*>(dch)[k];
    int4 s = reinterpret_cast<const int4*>(sch)[k];
    int b0 = d.x >> 8, b1 = d.y >> 8, b2 = d.z >> 8, b3 = d.w >> 8;
    int r0 = atomicAdd(&hist[b0], 1) + lbase[b0];
    int r1 = atomicAdd(&hist[b1], 1) + lbase[b1];
    int r2 = atomicAdd(&hist[b2], 1) + lbase[b2];
    int r3 = atomicAdd(&hist[b3], 1) + lbase[b3];
    if (r0 < C) payload[(long long)b0 * C + r0] = (s.x << 8) | (d.x & 255);
    if (r1 < C) payload[(long long)b1 * C + r1] = (s.y << 8) | (d.y & 255);
    if (r2 < C) payload[(long long)b2 * C + r2] = (s.z << 8) | (d.z & 255);
    if (r3 < C) payload[(long long)b3 * C + r3] = (s.w << 8) | (d.w & 255);
  }
  for (int k = (nv << 2) + tid; k < lim; k += FB_THREADS) {
    int d = dch[k], s = sch[k];
    int bk = d >> 8;
    int r = atomicAdd(&hist[bk], 1) + lbase[bk];
    if (r < C) payload[(long long)bk * C + r] = (s << 8) | (d & 255);
  }
  __syncthreads();
  for (int j = tid; j < nbf; j += FB_THREADS) {
    int c = hist[j];
    if (c) {
      int pc = (c + FB_PAD - 1) & ~(FB_PAD - 1);
      long long base = (long long)j * C;
      for (int k = lbase[j] + c; k < lbase[j] + pc; ++k)
        if (k < C) payload[base + k] = -1;
    }
  }
}

// ---------------- fallback: per-bucket counting sort (in-place) ------------
__global__ __launch_bounds__(256) void k_sort(
    int* __restrict__ payload, const int* __restrict__ gcur, int C,
    int n, const float* __restrict__ x,
    int* __restrict__ off_g, float* __restrict__ y) {
  __shared__ int stage[SORT_STAGE];
  __shared__ int hist[256];
  __shared__ int sbuf[2][256];
  __shared__ int cur[256];
  const int b = blockIdx.x, t = threadIdx.x;
  hist[t] = 0;
  __syncthreads();
  int* seg = payload + (long long)b * C;
  const int L = min(gcur[b], C);
  const int nv = L >> 2;
#pragma unroll 2
  for (int k = t; k < nv; k += 256) {
    int4 p = reinterpret_cast<const int4*>(seg)[k];
    reinterpret_cast<int4*>(stage)[k] = p;
    if (p.x >= 0) atomicAdd(&hist[p.x & 255], 1);
    if (p.y >= 0) atomicAdd(&hist[p.y & 255], 1);
    if (p.z >= 0) atomicAdd(&hist[p.z & 255], 1);
    if (p.w >= 0) atomicAdd(&hist[p.w & 255], 1);
  }
  for (int k = (nv << 2) + t; k < L; k += 256) {
    int p = seg[k];
    stage[k] = p;
    if (p >= 0) atomicAdd(&hist[p & 255], 1);
  }
  __syncthreads();
  sbuf[0][t] = hist[t];
  __syncthreads();
  int pi = 0;
  for (int d = 1; d < 256; d <<= 1) {
    int v = sbuf[pi][t];
    if (t >= d) v += sbuf[pi][t - d];
    sbuf[pi ^ 1][t] = v;
    pi ^= 1;
    __syncthreads();
  }
  const int inc = sbuf[pi][t];
  const int exc = inc - hist[t];
  cur[t] = exc;
  off_g[b * 257 + t] = exc;
  if (t == 255) off_g[b * 257 + 256] = inc;
  const int i = (b << 8) + t;
  if (i < n) y[i] = rsqrtf((float)(hist[t] + 1)) * x[i];
  __syncthreads();
#pragma unroll 4
  for (int k = t; k < L; k += 256) {
    int p = stage[k];
    if (p >= 0) {
      int pos = atomicAdd(&cur[p & 255], 1);
      seg[pos] = p;
    }
  }
}

// ---------------- fallback layer-1 scan reduce -----------------------------
__global__ __launch_bounds__(256) void k_reduce1(
    const int* __restrict__ payload, const int* __restrict__ off_g, int C,
    int n, const float* __restrict__ y, float2* __restrict__ ds) {
  __shared__ float S[256];
  const int b = blockIdx.x, t = threadIdx.x;
  S[t] = 0.0f;
  __syncthreads();
  const int L = off_g[b * 257 + 256];
  const int* seg = payload + (long long)b * C;
  const int lane = t & 63;
  for (int base = t - lane; base < L; base += 256) {
    int k = base + lane;
    bool valid = k < L;
    int p = 0;
    if (valid) p = __builtin_nontemporal_load(seg + k);
    int m = valid ? (p & 255) : 999;
    float v = valid ? y[p >> 8] : 0.0f;
    seg_scan1(m, v);
    int mn = __shfl_down(m, 1, 64);
    if ((lane == 63 || mn != m) && m < 256) atomicAdd(&S[m], v);
  }
  __syncthreads();
  const int i = (b << 8) + t;
  if (i < n) {
    int deg = off_g[b * 257 + t + 1] - off_g[b * 257 + t];
    float r = rsqrtf((float)(deg + 1));
    ds[i] = make_float2(r, r * (S[t] + y[i]));
  }
}

// ---------------- fallback layer-2 scan reduce -----------------------------
__global__ __launch_bounds__(256) void k_reduce2(
    const int* __restrict__ payload, const int* __restrict__ off_g, int C,
    int n, const float2* __restrict__ ds,
    const float* __restrict__ W1, const float* __restrict__ b1,
    const float* __restrict__ W2, const float* __restrict__ b2,
    float4* __restrict__ out) {
  __shared__ float S0[256], S1[256], S2[256], S3[256];
  const int b = blockIdx.x, t = threadIdx.x;
  S0[t] = 0.f; S1[t] = 0.f; S2[t] = 0.f; S3[t] = 0.f;
  __syncthreads();
  const float w10 = W1[0], w11 = W1[1], w12 = W1[2], w13 = W1[3];
  const float c10 = b1[0], c11 = b1[1], c12 = b1[2], c13 = b1[3];
  float w2[16];
#pragma unroll
  for (int k = 0; k < 16; ++k) w2[k] = W2[k];

  const int L = off_g[b * 257 + 256];
  const int* seg = payload + (long long)b * C;
  const int lane = t & 63;
  for (int base = t - lane; base < L; base += 256) {
    int k = base + lane;
    bool valid = k < L;
    int p = 0;
    if (valid) p = __builtin_nontemporal_load(seg + k);
    int m = valid ? (p & 255) : 999;
    float2 v = valid ? ds[p >> 8] : make_float2(0.f, 0.f);
    float r = valid ? v.x : 0.0f;
    float s = v.y;
    float h0 = fmaxf(fmaf(s, w10, c10), 0.f);
    float h1 = fmaxf(fmaf(s, w11, c11), 0.f);
    float h2 = fmaxf(fmaf(s, w12, c12), 0.f);
    float h3 = fmaxf(fmaf(s, w13, c13), 0.f);
    float gx = r * (h0 * w2[0] + h1 * w2[4] + h2 * w2[8]  + h3 * w2[12]);
    float gy = r * (h0 * w2[1] + h1 * w2[5] + h2 * w2[9]  + h3 * w2[13]);
    float gz = r * (h0 * w2[2] + h1 * w2[6] + h2 * w2[10] + h3 * w2[14]);
    float gw = r * (h0 * w2[3] + h1 * w2[7] + h2 * w2[11] + h3 * w2[15]);
    seg_scan4(m, gx, gy, gz, gw);
    int mn = __shfl_down(m, 1, 64);
    if ((lane == 63 || mn != m) && m < 256) {
      atomicAdd(&S0[m], gx);
      atomicAdd(&S1[m], gy);
      atomicAdd(&S2[m], gz);
      atomicAdd(&S3[m], gw);
    }
  }
  __syncthreads();
  const int i = (b << 8) + t;
  if (i < n) {
    float2 v = ds[i];
    float r = v.x, s = v.y;
    float h0 = fmaxf(fmaf(s, w10, c10), 0.f);
    float h1 = fmaxf(fmaf(s, w11, c11), 0.f);
    float h2 = fmaxf(fmaf(s, w12, c12), 0.f);
    float h3 = fmaxf(fmaf(s, w13, c13), 0.f);
    float gx = r * (h0 * w2[0] + h1 * w2[4] + h2 * w2[8]  + h3 * w2[12]);
    float gy = r * (h0 * w2[1] + h1 * w2[5] + h2 * w2[9]  + h3 * w2[13]);
    float gz = r * (h0 * w2[2] + h1 * w2[6] + h2 * w2[10] + h3 * w2[14]);
    float gw = r * (h0 * w2[3] + h1 * w2[7] + h2 * w2[11] + h3 * w2[15]);
    out[i] = make_float4(b2[0] + r * (S0[t] + gx),
                         b2[1] + r * (S1[t] + gy),
                         b2[2] + r * (S2[t] + gz),
                         b2[3] + r * (S3[t] + gw));
  }
}

extern "C" void kernel_launch(void* const* d_in, const int* in_sizes, int n_in,
                              void* d_out, int out_size, void* d_ws, size_t ws_size,
                              hipStream_t stream) {
  const float* x  = (const float*)d_in[0];
  const int*   ei = (const int*)d_in[1];
  const float* W1 = (const float*)d_in[2];
  const float* b1 = (const float*)d_in[3];
  const float* W2 = (const float*)d_in[4];
  const float* b2 = (const float*)d_in[5];

  const int n = in_sizes[0];
  const int E = in_sizes[1] / 2;
  const int* src = ei;
  const int* dst = ei + E;

  const int nbf = (n + 255) >> 8;    // fine buckets (256 nodes)
  const int nb1 = (n + 2047) >> 11;  // coarse buckets (2048 nodes)
  auto al = [](size_t v) { return (v + 255) & ~(size_t)255; };

  const size_t nn = (size_t)n;
  size_t sz_y   = al(nn * 4);
  size_t sz_ds  = al(nn * 8);

  // main-path capacities (exact counts + Poisson slack)
  long long mean1 = (long long)E / (nb1 > 0 ? nb1 : 1);
  long long C1ll = ((mean1 + 2048 + 1024) + 15) & ~15LL;
  long long mean2 = (long long)E / (nbf > 0 ? nbf : 1);
  long long C2ll = ((mean2 + 1024) + 15) & ~15LL;
  // zeroed region: gcur1(nb1) + gcur2(nbf) + deg(n), contiguous
  size_t sz_zero = al(((size_t)nb1 + nbf + nn) * 4);
  size_t need_main = al((size_t)nb1 * C1ll * 4) + al((size_t)nbf * C2ll * 4) +
                     sz_zero + sz_y + sz_ds;
  const bool main_ok = (n <= 524288) && (nb1 <= MAXNB1) &&
                       (need_main <= ws_size);

  if (main_ok) {
    const int C1 = (int)C1ll, C2 = (int)C2ll;
    char* p = (char*)d_ws;
    int*    pay1  = (int*)p;    p += al((size_t)nb1 * C1 * 4);
    int*    pay2  = (int*)p;    p += al((size_t)nbf * C2 * 4);
    int*    gcur1 = (int*)p;    // gcur1(nb1) | gcur2(nbf) | deg(n) contiguous
    int*    gcur2 = gcur1 + nb1;
    int*    deg_g = gcur2 + nbf;
    p += sz_zero;
    float*  y     = (float*)p;  p += sz_y;
    float2* ds    = (float2*)p; p += sz_ds;

    hipMemsetAsync(gcur1, 0, ((size_t)nb1 + nbf + nn) * 4, stream);

    int chunk = (int)(((long long)E + B1_BLOCKS - 1) / B1_BLOCKS);
    chunk = (chunk + 3) & ~3;

    k_bin1<<<B1_BLOCKS, B1_THREADS, 0, stream>>>(src, dst, E, chunk, nb1, C1,
                                                 gcur1, pay1);
    k_bin2d<<<nb1 * 2, B2_THREADS, 0, stream>>>(pay1, gcur1, C1, C2, gcur2,
                                                pay2, n, deg_g);
    k_y<<<(n + 255) / 256, 256, 0, stream>>>(n, deg_g, x, y);
    k_red1u<<<nbf, 256, 0, stream>>>(pay2, gcur2, C2, n, y, deg_g, ds);
    k_red2u<<<nbf, 256, 0, stream>>>(pay2, gcur2, C2, n, ds, W1, b1, W2, b2,
                                     (float4*)d_out);
    return;
  }

  // ---- fallback: round-7 flat binning + in-place sort + scan reduces ----
  {
    size_t sz_off = al((size_t)nbf * 257 * 4);
    size_t sz_gc  = al((size_t)nbf * 4);
    size_t fixed = sz_off + sz_y + sz_ds + sz_gc;
    double mean = (double)E / nbf;
    long long Cwant = (long long)(mean * 1.10) +
                      (long long)(FB_BLOCKS * FB_PAD / 2) + 512;
    size_t budget = ws_size > fixed ? ws_size - fixed - 4096 : 0;
    long long Cbud = (long long)(budget / ((size_t)nbf * 4));
    long long Cll = Cwant < Cbud ? Cwant : Cbud;
    if (Cll > SORT_STAGE) Cll = SORT_STAGE;
    int C = (int)(Cll & ~(long long)(FB_PAD - 1));

    char* p = (char*)d_ws;
    int*    pay2  = (int*)p;    p += al((size_t)nbf * C * 4);
    int*    gcur  = (int*)p;    p += sz_gc;
    int*    off_g = (int*)p;    p += sz_off;
    float*  y     = (float*)p;  p += sz_y;
    float2* ds    = (float2*)p; p += sz_ds;

    hipMemsetAsync(gcur, 0, (size_t)nbf * 4, stream);

    int chunk = (int)(((long long)E + FB_BLOCKS - 1) / FB_BLOCKS);
    chunk = (chunk + 3) & ~3;

    k_bin_flat<<<FB_BLOCKS, FB_THREADS, 0, stream>>>(src, dst, E, chunk, nbf,
                                                     C, gcur, pay2);
    k_sort<<<nbf, 256, 0, stream>>>(pay2, gcur, C, n, x, off_g, y);
    k_reduce1<<<nbf, 256, 0, stream>>>(pay2, off_g, C, n, y, ds);
    k_reduce2<<<nbf, 256, 0, stream>>>(pay2, off_g, C, n, ds, W1, b1, W2, b2,
                                       (float4*)d_out);
  }
}

// Round 7
// 594.454 us; speedup vs baseline: 1.1863x; 1.1863x over previous
//
#include <hip/hip_runtime.h>

// 2-layer GCNConv, N=500K, E=16M, Cin=1, Cout=4, fp32.
//
// Round-11: round-10 proved per-edge LDS *float* atomics are a ~3x dead
// end regardless of grid shape (344us == 345us at both shapes; CAS-loop
// replay). The DPP-scan reduces (106/85us) stay. Attack pass COUNT
// instead: bin2 (8-way split) + k_sort (counting sort) collapse into one
// k_csort -- per coarse bucket: histogram dh[2048] (native int LDS
// atomics, ~50us proven in round-8's k_cnt), 8x 256-wide exact scans ->
// off_g + y, then re-read segment (L2/L3-hot) and scatter each edge to
// its exact sorted slot in pay2. Deletes one full 16M-edge read+write
// pass and all gcur2/sentinel logic. bin1 + reduces byte-identical to
// the 524us round-7 champion.

#define B1_BLOCKS 512
#define B1_THREADS 1024
#define TILE1 16384
#define MAXNB1 256       // coarse buckets (2048 nodes); needs n <= 524288
#define SORT_STAGE 12032 // fallback k_sort LDS staging; fallback C <= this
// fallback (round-5 flat binning) constants
#define FB_BLOCKS 512
#define FB_THREADS 1024
#define FB_PAD 8
#define MAXNBF 2048

// ---------------- DPP segmented-scan helpers (VALU pipe) -------------------
template <int CTRL, int RM, int KOLD>
__device__ __forceinline__ void seg_step1(int m, float& a) {
  const int mm = __builtin_amdgcn_update_dpp(KOLD, m, CTRL, RM, 0xf, true);
  const float f = (mm == m) ? 1.0f : 0.0f;
  const float ba = __int_as_float(
      __builtin_amdgcn_update_dpp(0, __float_as_int(a), CTRL, RM, 0xf, true));
  a = fmaf(ba, f, a);
}

template <int CTRL, int RM, int KOLD>
__device__ __forceinline__ void seg_step4(int m, float& gx, float& gy,
                                          float& gz, float& gw) {
  const int mm = __builtin_amdgcn_update_dpp(KOLD, m, CTRL, RM, 0xf, true);
  const float f = (mm == m) ? 1.0f : 0.0f;
  const float bx = __int_as_float(
      __builtin_amdgcn_update_dpp(0, __float_as_int(gx), CTRL, RM, 0xf, true));
  const float by = __int_as_float(
      __builtin_amdgcn_update_dpp(0, __float_as_int(gy), CTRL, RM, 0xf, true));
  const float bz = __int_as_float(
      __builtin_amdgcn_update_dpp(0, __float_as_int(gz), CTRL, RM, 0xf, true));
  const float bw = __int_as_float(
      __builtin_amdgcn_update_dpp(0, __float_as_int(gw), CTRL, RM, 0xf, true));
  gx = fmaf(bx, f, gx);
  gy = fmaf(by, f, gy);
  gz = fmaf(bz, f, gz);
  gw = fmaf(bw, f, gw);
}

__device__ __forceinline__ void seg_scan1(int m, float& a) {
  seg_step1<0x111, 0xf, 0>(m, a);   // row_shr:1
  seg_step1<0x112, 0xf, 0>(m, a);   // row_shr:2
  seg_step1<0x114, 0xf, 0>(m, a);   // row_shr:4
  seg_step1<0x118, 0xf, 0>(m, a);   // row_shr:8
  seg_step1<0x142, 0xa, -1>(m, a);  // row_bcast15 -> rows 1,3
  seg_step1<0x143, 0xc, -1>(m, a);  // row_bcast31 -> rows 2,3
}

__device__ __forceinline__ void seg_scan4(int m, float& gx, float& gy,
                                          float& gz, float& gw) {
  seg_step4<0x111, 0xf, 0>(m, gx, gy, gz, gw);
  seg_step4<0x112, 0xf, 0>(m, gx, gy, gz, gw);
  seg_step4<0x114, 0xf, 0>(m, gx, gy, gz, gw);
  seg_step4<0x118, 0xf, 0>(m, gx, gy, gz, gw);
  seg_step4<0x142, 0xa, -1>(m, gx, gy, gz, gw);
  seg_step4<0x143, 0xc, -1>(m, gx, gy, gz, gw);
}

// ---------------- pass 1: coarse split (LDS-staged, coalesced flush) -------
__global__ __launch_bounds__(B1_THREADS) void k_bin1(
    const int* __restrict__ src, const int* __restrict__ dst, int E,
    int chunk, int nb1, int C1, int* __restrict__ gcur1,
    int* __restrict__ pay1) {
  __shared__ int out[TILE1];
  __shared__ int hist[MAXNB1], toff[MAXNB1], wcur[MAXNB1], gb[MAXNB1];
  __shared__ int sbuf[2][MAXNB1];
  const int tid = threadIdx.x;
  const long long e0 = (long long)blockIdx.x * chunk;
  long long reml = (long long)E - e0;
  const int lim = reml < 0 ? 0 : (reml < chunk ? (int)reml : chunk);
  const int* dch = dst + e0;
  const int* sch = src + e0;

  for (int tb = 0; tb < lim; tb += TILE1) {
    const int tcnt = min(TILE1, lim - tb);
    const int nv = tcnt >> 2;
    for (int j = tid; j < MAXNB1; j += B1_THREADS) hist[j] = 0;
    __syncthreads();

    // phase A: tile histogram of coarse keys
    const int* dt = dch + tb;
    for (int k = tid; k < nv; k += B1_THREADS) {
      int4 d = reinterpret_cast<const int4*>(dt)[k];
      atomicAdd(&hist[d.x >> 11], 1);
      atomicAdd(&hist[d.y >> 11], 1);
      atomicAdd(&hist[d.z >> 11], 1);
      atomicAdd(&hist[d.w >> 11], 1);
    }
    for (int k = (nv << 2) + tid; k < tcnt; k += B1_THREADS)
      atomicAdd(&hist[dt[k] >> 11], 1);
    __syncthreads();

    // phase B: exclusive scan (256-wide) + exact global range reservation
    if (tid < MAXNB1) sbuf[0][tid] = hist[tid];
    __syncthreads();
    int pi = 0;
    for (int dd = 1; dd < MAXNB1; dd <<= 1) {
      if (tid < MAXNB1) {
        int v = sbuf[pi][tid];
        if (tid >= dd) v += sbuf[pi][tid - dd];
        sbuf[pi ^ 1][tid] = v;
      }
      pi ^= 1;
      __syncthreads();
    }
    if (tid < MAXNB1) {
      int c = hist[tid];
      int exc = sbuf[pi][tid] - c;
      toff[tid] = exc;
      wcur[tid] = exc;
      gb[tid] = c ? atomicAdd(&gcur1[tid], c) : 0;
    }
    __syncthreads();

    // phase C: rank + place packed (src<<11 | dst&2047) into LDS out
    const int* st = sch + tb;
    for (int k = tid; k < nv; k += B1_THREADS) {
      int4 d = reinterpret_cast<const int4*>(dt)[k];
      int4 s = reinterpret_cast<const int4*>(st)[k];
      int r0 = atomicAdd(&wcur[d.x >> 11], 1);
      int r1 = atomicAdd(&wcur[d.y >> 11], 1);
      int r2 = atomicAdd(&wcur[d.z >> 11], 1);
      int r3 = atomicAdd(&wcur[d.w >> 11], 1);
      out[r0] = (s.x << 11) | (d.x & 2047);
      out[r1] = (s.y << 11) | (d.y & 2047);
      out[r2] = (s.z << 11) | (d.z & 2047);
      out[r3] = (s.w << 11) | (d.w & 2047);
    }
    for (int k = (nv << 2) + tid; k < tcnt; k += B1_THREADS) {
      int d = dt[k], s = st[k];
      int r = atomicAdd(&wcur[d >> 11], 1);
      out[r] = (s << 11) | (d & 2047);
    }
    __syncthreads();

    // phase D: wave-per-bucket coalesced copy LDS -> global
    const int wv = tid >> 6, lane = tid & 63;
    for (int j = wv; j < nb1; j += 16) {
      const int c = wcur[j] - toff[j];
      if (!c) continue;
      const int gbase = gb[j];
      const long long pbase = (long long)j * C1;
      for (int q = lane; q < c; q += 64) {
        int gi = gbase + q;
        if (gi < C1) pay1[pbase + gi] = out[toff[j] + q];
      }
    }
    __syncthreads();
  }
}

// ---------------- fused counting sort: coarse seg -> node-sorted fine ------
// One block per coarse bucket (2048 nodes = 8 fine buckets of 256).
// Pass A: histogram dh[2048] (native int LDS atomics).
// Scan: 8 independent 256-wide exact scans -> off_g, y.
// Pass B: re-read segment (L2/L3-hot), scatter to exact sorted slot.
__global__ __launch_bounds__(1024) void k_csort(
    const int* __restrict__ pay1, const int* __restrict__ gcur1, int C1,
    int C2, int n, const float* __restrict__ x,
    int* __restrict__ off_g, float* __restrict__ y,
    int* __restrict__ pay2) {
  __shared__ int dh[2048];
  __shared__ int off2[2048];
  __shared__ int sb[2][1024];
  const int b = blockIdx.x, t = threadIdx.x;
  const int L = min(gcur1[b], C1);
  const int* seg = pay1 + (long long)b * C1;
  dh[t] = 0;
  dh[t + 1024] = 0;
  __syncthreads();

  // pass A: histogram of node-within-bucket keys
  const int nv = L >> 2;
  for (int k = t; k < nv; k += 1024) {
    int4 p = reinterpret_cast<const int4*>(seg)[k];
    atomicAdd(&dh[p.x & 2047], 1);
    atomicAdd(&dh[p.y & 2047], 1);
    atomicAdd(&dh[p.z & 2047], 1);
    atomicAdd(&dh[p.w & 2047], 1);
  }
  for (int k = (nv << 2) + t; k < L; k += 1024)
    atomicAdd(&dh[seg[k] & 2047], 1);
  __syncthreads();

  // scan: two rounds of 4 parallel 256-wide inclusive scans
#pragma unroll
  for (int r = 0; r < 2; ++r) {
    const int base = r << 10;
    const int c0 = dh[base + t];
    sb[0][t] = c0;
    __syncthreads();
    int pi = 0;
    for (int d = 1; d < 256; d <<= 1) {
      int v = sb[pi][t];
      if ((t & 255) >= d) v += sb[pi][t - d];
      sb[pi ^ 1][t] = v;
      pi ^= 1;
      __syncthreads();
    }
    const int inc = sb[pi][t];
    const int exc = inc - c0;
    off2[base + t] = exc;
    const int f = (b << 3) + ((base + t) >> 8);
    const int tt = t & 255;
    off_g[f * 257 + tt] = min(exc, C2);
    if (tt == 255) off_g[f * 257 + 256] = min(inc, C2);
    const int i = (b << 11) + base + t;
    if (i < n) y[i] = rsqrtf((float)(c0 + 1)) * x[i];
    __syncthreads();
  }

  // pass B: re-read + scatter to exact sorted slot (off2 doubles as cursor)
  for (int k = t; k < nv; k += 1024) {
    int4 p = reinterpret_cast<const int4*>(seg)[k];
#pragma unroll
    for (int c = 0; c < 4; ++c) {
      const int pv = (c == 0) ? p.x : (c == 1) ? p.y : (c == 2) ? p.z : p.w;
      const int j = pv & 2047;
      const int pos = atomicAdd(&off2[j], 1);
      if (pos < C2)
        pay2[(long long)((b << 3) + (j >> 8)) * C2 + pos] =
            ((pv >> 11) << 8) | (j & 255);
    }
  }
  for (int k = (nv << 2) + t; k < L; k += 1024) {
    const int pv = seg[k];
    const int j = pv & 2047;
    const int pos = atomicAdd(&off2[j], 1);
    if (pos < C2)
      pay2[(long long)((b << 3) + (j >> 8)) * C2 + pos] =
          ((pv >> 11) << 8) | (j & 255);
  }
}

// ---------------- layer-1 segmented sum -> ds = (dinv, s) ------------------
__global__ __launch_bounds__(256) void k_reduce1(
    const int* __restrict__ payload, const int* __restrict__ off_g, int C,
    int n, const float* __restrict__ y, float2* __restrict__ ds) {
  __shared__ float S[256];
  const int b = blockIdx.x, t = threadIdx.x;
  S[t] = 0.0f;
  __syncthreads();
  const int L = off_g[b * 257 + 256];
  const int* seg = payload + (long long)b * C;
  const int lane = t & 63;
  for (int base = t - lane; base < L; base += 256) {
    int k = base + lane;
    bool valid = k < L;
    int p = 0;
    if (valid) p = __builtin_nontemporal_load(seg + k);
    int m = valid ? (p & 255) : 999;
    float v = valid ? y[p >> 8] : 0.0f;
    seg_scan1(m, v);  // DPP segmented scan (VALU pipe)
    int mn = __shfl_down(m, 1, 64);
    if ((lane == 63 || mn != m) && m < 256) atomicAdd(&S[m], v);
  }
  __syncthreads();
  const int i = (b << 8) + t;
  if (i < n) {
    int deg = off_g[b * 257 + t + 1] - off_g[b * 257 + t];
    float r = rsqrtf((float)(deg + 1));
    ds[i] = make_float2(r, r * (S[t] + y[i]));
  }
}

// ---------------- layer-2: gather ds, compute message, segmented sum -------
__global__ __launch_bounds__(256) void k_reduce2(
    const int* __restrict__ payload, const int* __restrict__ off_g, int C,
    int n, const float2* __restrict__ ds,
    const float* __restrict__ W1, const float* __restrict__ b1,
    const float* __restrict__ W2, const float* __restrict__ b2,
    float4* __restrict__ out) {
  __shared__ float S0[256], S1[256], S2[256], S3[256];
  const int b = blockIdx.x, t = threadIdx.x;
  S0[t] = 0.f; S1[t] = 0.f; S2[t] = 0.f; S3[t] = 0.f;
  __syncthreads();
  const float w10 = W1[0], w11 = W1[1], w12 = W1[2], w13 = W1[3];
  const float c10 = b1[0], c11 = b1[1], c12 = b1[2], c13 = b1[3];
  float w2[16];
#pragma unroll
  for (int k = 0; k < 16; ++k) w2[k] = W2[k];

  const int L = off_g[b * 257 + 256];
  const int* seg = payload + (long long)b * C;
  const int lane = t & 63;
  for (int base = t - lane; base < L; base += 256) {
    int k = base + lane;
    bool valid = k < L;
    int p = 0;
    if (valid) p = __builtin_nontemporal_load(seg + k);
    int m = valid ? (p & 255) : 999;
    float2 v = valid ? ds[p >> 8] : make_float2(0.f, 0.f);
    float r = valid ? v.x : 0.0f;  // r=0 zeroes the whole message
    float s = v.y;
    float h0 = fmaxf(fmaf(s, w10, c10), 0.f);
    float h1 = fmaxf(fmaf(s, w11, c11), 0.f);
    float h2 = fmaxf(fmaf(s, w12, c12), 0.f);
    float h3 = fmaxf(fmaf(s, w13, c13), 0.f);
    float gx = r * (h0 * w2[0] + h1 * w2[4] + h2 * w2[8]  + h3 * w2[12]);
    float gy = r * (h0 * w2[1] + h1 * w2[5] + h2 * w2[9]  + h3 * w2[13]);
    float gz = r * (h0 * w2[2] + h1 * w2[6] + h2 * w2[10] + h3 * w2[14]);
    float gw = r * (h0 * w2[3] + h1 * w2[7] + h2 * w2[11] + h3 * w2[15]);
    seg_scan4(m, gx, gy, gz, gw);  // DPP segmented scan (VALU pipe)
    int mn = __shfl_down(m, 1, 64);
    if ((lane == 63 || mn != m) && m < 256) {
      atomicAdd(&S0[m], gx);
      atomicAdd(&S1[m], gy);
      atomicAdd(&S2[m], gz);
      atomicAdd(&S3[m], gw);
    }
  }
  __syncthreads();
  const int i = (b << 8) + t;
  if (i < n) {
    float2 v = ds[i];
    float r = v.x, s = v.y;
    float h0 = fmaxf(fmaf(s, w10, c10), 0.f);
    float h1 = fmaxf(fmaf(s, w11, c11), 0.f);
    float h2 = fmaxf(fmaf(s, w12, c12), 0.f);
    float h3 = fmaxf(fmaf(s, w13, c13), 0.f);
    float gx = r * (h0 * w2[0] + h1 * w2[4] + h2 * w2[8]  + h3 * w2[12]);
    float gy = r * (h0 * w2[1] + h1 * w2[5] + h2 * w2[9]  + h3 * w2[13]);
    float gz = r * (h0 * w2[2] + h1 * w2[6] + h2 * w2[10] + h3 * w2[14]);
    float gw = r * (h0 * w2[3] + h1 * w2[7] + h2 * w2[11] + h3 * w2[15]);
    out[i] = make_float4(b2[0] + r * (S0[t] + gx),
                         b2[1] + r * (S1[t] + gy),
                         b2[2] + r * (S2[t] + gz),
                         b2[3] + r * (S3[t] + gw));
  }
}

// ---------------- fallback flat binning (round-5, proven) ------------------
__global__ __launch_bounds__(FB_THREADS) void k_bin_flat(
    const int* __restrict__ src, const int* __restrict__ dst, int E,
    int chunk, int nbf, int C, int* __restrict__ gcur,
    int* __restrict__ payload) {
  __shared__ int hist[MAXNBF];
  __shared__ int lbase[MAXNBF];
  const int tid = threadIdx.x;
  const long long e0 = (long long)blockIdx.x * chunk;
  long long rem = (long long)E - e0;
  int lim = rem < 0 ? 0 : (rem < chunk ? (int)rem : chunk);
  for (int j = tid; j < nbf; j += FB_THREADS) hist[j] = 0;
  __syncthreads();
  const int* dch = dst + e0;
  const int* sch = src + e0;
  const int nv = lim >> 2;
  for (int k = tid; k < nv; k += FB_THREADS) {
    int4 d = reinterpret_cast<const int4*>(dch)[k];
    atomicAdd(&hist[d.x >> 8], 1);
    atomicAdd(&hist[d.y >> 8], 1);
    atomicAdd(&hist[d.z >> 8], 1);
    atomicAdd(&hist[d.w >> 8], 1);
  }
  for (int k = (nv << 2) + tid; k < lim; k += FB_THREADS)
    atomicAdd(&hist[dch[k] >> 8], 1);
  __syncthreads();
  for (int j = tid; j < nbf; j += FB_THREADS) {
    int c = hist[j];
    lbase[j] = c ? atomicAdd(&gcur[j], (c + FB_PAD - 1) & ~(FB_PAD - 1)) : 0;
    hist[j] = 0;
  }
  __syncthreads();
  for (int k = tid; k < nv; k += FB_THREADS) {
    int4 d = reinterpret_cast<const int4*>(dch)[k];
    int4 s = reinterpret_cast<const int4*>(sch)[k];
    int b0 = d.x >> 8, b1 = d.y >> 8, b2 = d.z >> 8, b3 = d.w >> 8;
    int r0 = atomicAdd(&hist[b0], 1) + lbase[b0];
    int r1 = atomicAdd(&hist[b1], 1) + lbase[b1];
    int r2 = atomicAdd(&hist[b2], 1) + lbase[b2];
    int r3 = atomicAdd(&hist[b3], 1) + lbase[b3];
    if (r0 < C) payload[(long long)b0 * C + r0] = (s.x << 8) | (d.x & 255);
    if (r1 < C) payload[(long long)b1 * C + r1] = (s.y << 8) | (d.y & 255);
    if (r2 < C) payload[(long long)b2 * C + r2] = (s.z << 8) | (d.z & 255);
    if (r3 < C) payload[(long long)b3 * C + r3] = (s.w << 8) | (d.w & 255);
  }
  for (int k = (nv << 2) + tid; k < lim; k += FB_THREADS) {
    int d = dch[k], s = sch[k];
    int bk = d >> 8;
    int r = atomicAdd(&hist[bk], 1) + lbase[bk];
    if (r < C) payload[(long long)bk * C + r] = (s << 8) | (d & 255);
  }
  __syncthreads();
  for (int j = tid; j < nbf; j += FB_THREADS) {
    int c = hist[j];
    if (c) {
      int pc = (c + FB_PAD - 1) & ~(FB_PAD - 1);
      long long base = (long long)j * C;
      for (int k = lbase[j] + c; k < lbase[j] + pc; ++k)
        if (k < C) payload[base + k] = -1;
    }
  }
}

// ---------------- fallback: per-bucket counting sort (in-place) ------------
__global__ __launch_bounds__(256) void k_sort(
    int* __restrict__ payload, const int* __restrict__ gcur, int C,
    int n, const float* __restrict__ x,
    int* __restrict__ off_g, float* __restrict__ y) {
  __shared__ int stage[SORT_STAGE];
  __shared__ int hist[256];
  __shared__ int sbuf[2][256];
  __shared__ int cur[256];
  const int b = blockIdx.x, t = threadIdx.x;
  hist[t] = 0;
  __syncthreads();
  int* seg = payload + (long long)b * C;
  const int L = min(gcur[b], C);
  const int nv = L >> 2;
#pragma unroll 2
  for (int k = t; k < nv; k += 256) {
    int4 p = reinterpret_cast<const int4*>(seg)[k];
    reinterpret_cast<int4*>(stage)[k] = p;
    if (p.x >= 0) atomicAdd(&hist[p.x & 255], 1);
    if (p.y >= 0) atomicAdd(&hist[p.y & 255], 1);
    if (p.z >= 0) atomicAdd(&hist[p.z & 255], 1);
    if (p.w >= 0) atomicAdd(&hist[p.w & 255], 1);
  }
  for (int k = (nv << 2) + t; k < L; k += 256) {
    int p = seg[k];
    stage[k] = p;
    if (p >= 0) atomicAdd(&hist[p & 255], 1);
  }
  __syncthreads();
  sbuf[0][t] = hist[t];
  __syncthreads();
  int pi = 0;
  for (int d = 1; d < 256; d <<= 1) {
    int v = sbuf[pi][t];
    if (t >= d) v += sbuf[pi][t - d];
    sbuf[pi ^ 1][t] = v;
    pi ^= 1;
    __syncthreads();
  }
  const int inc = sbuf[pi][t];
  const int exc = inc - hist[t];
  cur[t] = exc;
  off_g[b * 257 + t] = exc;
  if (t == 255) off_g[b * 257 + 256] = inc;
  const int i = (b << 8) + t;
  if (i < n) y[i] = rsqrtf((float)(hist[t] + 1)) * x[i];
  __syncthreads();
#pragma unroll 4
  for (int k = t; k < L; k += 256) {
    int p = stage[k];
    if (p >= 0) {
      int pos = atomicAdd(&cur[p & 255], 1);
      seg[pos] = p;
    }
  }
}

extern "C" void kernel_launch(void* const* d_in, const int* in_sizes, int n_in,
                              void* d_out, int out_size, void* d_ws, size_t ws_size,
                              hipStream_t stream) {
  const float* x  = (const float*)d_in[0];
  const int*   ei = (const int*)d_in[1];
  const float* W1 = (const float*)d_in[2];
  const float* b1 = (const float*)d_in[3];
  const float* W2 = (const float*)d_in[4];
  const float* b2 = (const float*)d_in[5];

  const int n = in_sizes[0];
  const int E = in_sizes[1] / 2;
  const int* src = ei;
  const int* dst = ei + E;

  const int nbf = (n + 255) >> 8;    // fine buckets (256 nodes)
  const int nb1 = (n + 2047) >> 11;  // coarse buckets (2048 nodes)
  auto al = [](size_t v) { return (v + 255) & ~(size_t)255; };

  const size_t nn = (size_t)n;
  size_t sz_off = al((size_t)nbf * 257 * 4);
  size_t sz_y   = al(nn * 4);
  size_t sz_ds  = al(nn * 8);

  // main-path capacities (exact counts + Poisson slack)
  long long mean1 = (long long)E / (nb1 > 0 ? nb1 : 1);
  long long C1ll = ((mean1 + 2048 + 1024) + 15) & ~15LL;
  long long mean2 = (long long)E / (nbf > 0 ? nbf : 1);
  long long C2ll = ((mean2 + 1024) + 15) & ~15LL;
  size_t need_main = al((size_t)nb1 * C1ll * 4) + al((size_t)nbf * C2ll * 4) +
                     al((size_t)nb1 * 4) + sz_off + sz_y + sz_ds;
  const bool main_ok = (n <= 524288) && (nb1 <= MAXNB1) &&
                       ((nb1 << 3) >= nbf) && (need_main <= ws_size);

  if (main_ok) {
    const int C1 = (int)C1ll, C2 = (int)C2ll;
    char* p = (char*)d_ws;
    int*    pay1  = (int*)p;    p += al((size_t)nb1 * C1 * 4);
    int*    pay2  = (int*)p;    p += al((size_t)nbf * C2 * 4);
    int*    gcur1 = (int*)p;    p += al((size_t)nb1 * 4);
    int*    off_g = (int*)p;    p += sz_off;
    float*  y     = (float*)p;  p += sz_y;
    float2* ds    = (float2*)p; p += sz_ds;

    hipMemsetAsync(gcur1, 0, (size_t)nb1 * 4, stream);

    int chunk = (int)(((long long)E + B1_BLOCKS - 1) / B1_BLOCKS);
    chunk = (chunk + 3) & ~3;

    k_bin1<<<B1_BLOCKS, B1_THREADS, 0, stream>>>(src, dst, E, chunk, nb1, C1,
                                                 gcur1, pay1);
    k_csort<<<nb1, 1024, 0, stream>>>(pay1, gcur1, C1, C2, n, x, off_g, y,
                                      pay2);
    k_reduce1<<<nbf, 256, 0, stream>>>(pay2, off_g, C2, n, y, ds);
    k_reduce2<<<nbf, 256, 0, stream>>>(pay2, off_g, C2, n, ds, W1, b1, W2, b2,
                                       (float4*)d_out);
    return;
  }

  // ---- fallback: round-7 flat binning + in-place sort + scan reduces ----
  {
    size_t sz_gc  = al((size_t)nbf * 4);
    size_t fixed = sz_off + sz_y + sz_ds + sz_gc;
    double mean = (double)E / nbf;
    long long Cwant = (long long)(mean * 1.10) +
                      (long long)(FB_BLOCKS * FB_PAD / 2) + 512;
    size_t budget = ws_size > fixed ? ws_size - fixed - 4096 : 0;
    long long Cbud = (long long)(budget / ((size_t)nbf * 4));
    long long Cll = Cwant < Cbud ? Cwant : Cbud;
    if (Cll > SORT_STAGE) Cll = SORT_STAGE;
    int C = (int)(Cll & ~(long long)(FB_PAD - 1));

    char* p = (char*)d_ws;
    int*    pay2  = (int*)p;    p += al((size_t)nbf * C * 4);
    int*    gcur  = (int*)p;    p += sz_gc;
    int*    off_g = (int*)p;    p += sz_off;
    float*  y     = (float*)p;  p += sz_y;
    float2* ds    = (float2*)p; p += sz_ds;

    hipMemsetAsync(gcur, 0, (size_t)nbf * 4, stream);

    int chunk = (int)(((long long)E + FB_BLOCKS - 1) / FB_BLOCKS);
    chunk = (chunk + 3) & ~3;

    k_bin_flat<<<FB_BLOCKS, FB_THREADS, 0, stream>>>(src, dst, E, chunk, nbf,
                                                     C, gcur, pay2);
    k_sort<<<nbf, 256, 0, stream>>>(pay2, gcur, C, n, x, off_g, y);
    k_reduce1<<<nbf, 256, 0, stream>>>(pay2, off_g, C, n, y, ds);
    k_reduce2<<<nbf, 256, 0, stream>>>(pay2, off_g, C, n, ds, W1, b1, W2, b2,
                                       (float4*)d_out);
  }
}

// Round 8
// 578.678 us; speedup vs baseline: 1.2186x; 1.0273x over previous
//
#include <hip/hip_runtime.h>

// 2-layer GCNConv, N=500K, E=16M, Cin=1, Cout=4, fp32.
//
// Round-12: back to the round-7 champion (bin1 -> bin2 -> sort ->
// reduce1 -> reduce2, DPP-scan reduces, 524us) with one polish: the
// layer-2 per-edge message dinv_src*(W2^T relu(W1 s_src + b1)) depends
// on src ONLY, so the MLP hoists out of the 16M-edge loop into a
// per-node precompute (g[n] float4) fused into k_reduce1's epilogue
// (32x fewer MLP evals). k_reduce2g's hot loop is just gather-g +
// DPP-scan + boundary atomics; ds[] is deleted. Rounds 6/8/9/10/11
// falsified all structural alternatives (unsorted atomics ~3x; global
// scatter-sort = 427MB partial-sector writes; fused csort no better).

#define B1_BLOCKS 512
#define B1_THREADS 1024
#define TILE1 16384
#define B2_THREADS 1024
#define TILE2 16384
#define MAXNB1 256       // coarse buckets (2048 nodes); needs n <= 524288
#define SORT_STAGE 12032 // ints staged in LDS by k_sort; C2 <= this
// fallback (round-5 flat binning) constants
#define FB_BLOCKS 512
#define FB_THREADS 1024
#define FB_PAD 8
#define MAXNBF 2048

// ---------------- DPP segmented-scan helpers (VALU pipe, no LDS) -----------
template <int CTRL, int RM, int KOLD>
__device__ __forceinline__ void seg_step1(int m, float& a) {
  const int mm = __builtin_amdgcn_update_dpp(KOLD, m, CTRL, RM, 0xf, true);
  const float f = (mm == m) ? 1.0f : 0.0f;
  const float ba = __int_as_float(
      __builtin_amdgcn_update_dpp(0, __float_as_int(a), CTRL, RM, 0xf, true));
  a = fmaf(ba, f, a);
}

template <int CTRL, int RM, int KOLD>
__device__ __forceinline__ void seg_step4(int m, float& gx, float& gy,
                                          float& gz, float& gw) {
  const int mm = __builtin_amdgcn_update_dpp(KOLD, m, CTRL, RM, 0xf, true);
  const float f = (mm == m) ? 1.0f : 0.0f;
  const float bx = __int_as_float(
      __builtin_amdgcn_update_dpp(0, __float_as_int(gx), CTRL, RM, 0xf, true));
  const float by = __int_as_float(
      __builtin_amdgcn_update_dpp(0, __float_as_int(gy), CTRL, RM, 0xf, true));
  const float bz = __int_as_float(
      __builtin_amdgcn_update_dpp(0, __float_as_int(gz), CTRL, RM, 0xf, true));
  const float bw = __int_as_float(
      __builtin_amdgcn_update_dpp(0, __float_as_int(gw), CTRL, RM, 0xf, true));
  gx = fmaf(bx, f, gx);
  gy = fmaf(by, f, gy);
  gz = fmaf(bz, f, gz);
  gw = fmaf(bw, f, gw);
}

__device__ __forceinline__ void seg_scan1(int m, float& a) {
  seg_step1<0x111, 0xf, 0>(m, a);   // row_shr:1
  seg_step1<0x112, 0xf, 0>(m, a);   // row_shr:2
  seg_step1<0x114, 0xf, 0>(m, a);   // row_shr:4
  seg_step1<0x118, 0xf, 0>(m, a);   // row_shr:8
  seg_step1<0x142, 0xa, -1>(m, a);  // row_bcast15 -> rows 1,3
  seg_step1<0x143, 0xc, -1>(m, a);  // row_bcast31 -> rows 2,3
}

__device__ __forceinline__ void seg_scan4(int m, float& gx, float& gy,
                                          float& gz, float& gw) {
  seg_step4<0x111, 0xf, 0>(m, gx, gy, gz, gw);
  seg_step4<0x112, 0xf, 0>(m, gx, gy, gz, gw);
  seg_step4<0x114, 0xf, 0>(m, gx, gy, gz, gw);
  seg_step4<0x118, 0xf, 0>(m, gx, gy, gz, gw);
  seg_step4<0x142, 0xa, -1>(m, gx, gy, gz, gw);
  seg_step4<0x143, 0xc, -1>(m, gx, gy, gz, gw);
}

// ---------------- pass 1: coarse split (LDS-staged, coalesced flush) -------
__global__ __launch_bounds__(B1_THREADS) void k_bin1(
    const int* __restrict__ src, const int* __restrict__ dst, int E,
    int chunk, int nb1, int C1, int* __restrict__ gcur1,
    int* __restrict__ pay1) {
  __shared__ int out[TILE1];
  __shared__ int hist[MAXNB1], toff[MAXNB1], wcur[MAXNB1], gb[MAXNB1];
  __shared__ int sbuf[2][MAXNB1];
  const int tid = threadIdx.x;
  const long long e0 = (long long)blockIdx.x * chunk;
  long long reml = (long long)E - e0;
  const int lim = reml < 0 ? 0 : (reml < chunk ? (int)reml : chunk);
  const int* dch = dst + e0;
  const int* sch = src + e0;

  for (int tb = 0; tb < lim; tb += TILE1) {
    const int tcnt = min(TILE1, lim - tb);
    const int nv = tcnt >> 2;
    for (int j = tid; j < MAXNB1; j += B1_THREADS) hist[j] = 0;
    __syncthreads();

    // phase A: tile histogram of coarse keys
    const int* dt = dch + tb;
    for (int k = tid; k < nv; k += B1_THREADS) {
      int4 d = reinterpret_cast<const int4*>(dt)[k];
      atomicAdd(&hist[d.x >> 11], 1);
      atomicAdd(&hist[d.y >> 11], 1);
      atomicAdd(&hist[d.z >> 11], 1);
      atomicAdd(&hist[d.w >> 11], 1);
    }
    for (int k = (nv << 2) + tid; k < tcnt; k += B1_THREADS)
      atomicAdd(&hist[dt[k] >> 11], 1);
    __syncthreads();

    // phase B: exclusive scan (256-wide) + exact global range reservation
    if (tid < MAXNB1) sbuf[0][tid] = hist[tid];
    __syncthreads();
    int pi = 0;
    for (int dd = 1; dd < MAXNB1; dd <<= 1) {
      if (tid < MAXNB1) {
        int v = sbuf[pi][tid];
        if (tid >= dd) v += sbuf[pi][tid - dd];
        sbuf[pi ^ 1][tid] = v;
      }
      pi ^= 1;
      __syncthreads();
    }
    if (tid < MAXNB1) {
      int c = hist[tid];
      int exc = sbuf[pi][tid] - c;
      toff[tid] = exc;
      wcur[tid] = exc;
      gb[tid] = c ? atomicAdd(&gcur1[tid], c) : 0;
    }
    __syncthreads();

    // phase C: rank + place packed (src<<11 | dst&2047) into LDS out
    const int* st = sch + tb;
    for (int k = tid; k < nv; k += B1_THREADS) {
      int4 d = reinterpret_cast<const int4*>(dt)[k];
      int4 s = reinterpret_cast<const int4*>(st)[k];
      int r0 = atomicAdd(&wcur[d.x >> 11], 1);
      int r1 = atomicAdd(&wcur[d.y >> 11], 1);
      int r2 = atomicAdd(&wcur[d.z >> 11], 1);
      int r3 = atomicAdd(&wcur[d.w >> 11], 1);
      out[r0] = (s.x << 11) | (d.x & 2047);
      out[r1] = (s.y << 11) | (d.y & 2047);
      out[r2] = (s.z << 11) | (d.z & 2047);
      out[r3] = (s.w << 11) | (d.w & 2047);
    }
    for (int k = (nv << 2) + tid; k < tcnt; k += B1_THREADS) {
      int d = dt[k], s = st[k];
      int r = atomicAdd(&wcur[d >> 11], 1);
      out[r] = (s << 11) | (d & 2047);
    }
    __syncthreads();

    // phase D: wave-per-bucket coalesced copy LDS -> global
    const int wv = tid >> 6, lane = tid & 63;
    for (int j = wv; j < nb1; j += 16) {
      const int c = wcur[j] - toff[j];
      if (!c) continue;
      const int gbase = gb[j];
      const long long pbase = (long long)j * C1;
      for (int q = lane; q < c; q += 64) {
        int gi = gbase + q;
        if (gi < C1) pay1[pbase + gi] = out[toff[j] + q];
      }
    }
    __syncthreads();
  }
}

// ---------------- pass 2: fine split (8 buckets per coarse) ----------------
__global__ __launch_bounds__(B2_THREADS) void k_bin2(
    const int* __restrict__ pay1, const int* __restrict__ gcur1, int C1,
    int C2, int* __restrict__ gcur2, int* __restrict__ pay2) {
  __shared__ int out[TILE2];
  __shared__ int hist[8], toff9[9], wcur[8], gb[8];
  const int cb = blockIdx.x >> 1;
  const int half = blockIdx.x & 1;
  const int tid = threadIdx.x;
  const int Lc = min(gcur1[cb], C1);
  int mid = ((Lc >> 1) + 3) & ~3;
  if (mid > Lc) mid = Lc;
  const int h0 = half ? mid : 0;
  const int h1 = half ? Lc : mid;
  const int* seg = pay1 + (long long)cb * C1;

  for (int tb = h0; tb < h1; tb += TILE2) {
    const int tcnt = min(TILE2, h1 - tb);
    const int nv = tcnt >> 2;
    if (tid < 8) hist[tid] = 0;
    __syncthreads();
    const int* pt = seg + tb;

    for (int k = tid; k < nv; k += B2_THREADS) {
      int4 p = reinterpret_cast<const int4*>(pt)[k];
      atomicAdd(&hist[(p.x >> 8) & 7], 1);
      atomicAdd(&hist[(p.y >> 8) & 7], 1);
      atomicAdd(&hist[(p.z >> 8) & 7], 1);
      atomicAdd(&hist[(p.w >> 8) & 7], 1);
    }
    for (int k = (nv << 2) + tid; k < tcnt; k += B2_THREADS)
      atomicAdd(&hist[(pt[k] >> 8) & 7], 1);
    __syncthreads();

    if (tid == 0) {
      int run = 0;
      for (int j = 0; j < 8; ++j) { toff9[j] = run; run += hist[j]; }
      toff9[8] = run;
    }
    __syncthreads();
    if (tid < 8) {
      wcur[tid] = toff9[tid];
      gb[tid] = hist[tid] ? atomicAdd(&gcur2[cb * 8 + tid], hist[tid]) : 0;
    }
    __syncthreads();

    for (int k = tid; k < nv; k += B2_THREADS) {
      int4 p = reinterpret_cast<const int4*>(pt)[k];
      out[atomicAdd(&wcur[(p.x >> 8) & 7], 1)] = ((p.x >> 11) << 8) | (p.x & 255);
      out[atomicAdd(&wcur[(p.y >> 8) & 7], 1)] = ((p.y >> 11) << 8) | (p.y & 255);
      out[atomicAdd(&wcur[(p.z >> 8) & 7], 1)] = ((p.z >> 11) << 8) | (p.z & 255);
      out[atomicAdd(&wcur[(p.w >> 8) & 7], 1)] = ((p.w >> 11) << 8) | (p.w & 255);
    }
    for (int k = (nv << 2) + tid; k < tcnt; k += B2_THREADS) {
      int p = pt[k];
      out[atomicAdd(&wcur[(p >> 8) & 7], 1)] = ((p >> 11) << 8) | (p & 255);
    }
    __syncthreads();

    const int total = toff9[8];
    for (int q = tid; q < total; q += B2_THREADS) {
      int j = (q >= toff9[4]) ? 4 : 0;
      j += (q >= toff9[j + 2]) ? 2 : 0;
      j += (q >= toff9[j + 1]) ? 1 : 0;
      int o = gb[j] + (q - toff9[j]);
      if (o < C2) pay2[(long long)(cb * 8 + j) * C2 + o] = out[q];
    }
    __syncthreads();
  }
}

// ---------------- fallback flat binning (round-5, proven) ------------------
__global__ __launch_bounds__(FB_THREADS) void k_bin_flat(
    const int* __restrict__ src, const int* __restrict__ dst, int E,
    int chunk, int nbf, int C, int* __restrict__ gcur,
    int* __restrict__ payload) {
  __shared__ int hist[MAXNBF];
  __shared__ int lbase[MAXNBF];
  const int tid = threadIdx.x;
  const long long e0 = (long long)blockIdx.x * chunk;
  long long rem = (long long)E - e0;
  int lim = rem < 0 ? 0 : (rem < chunk ? (int)rem : chunk);
  for (int j = tid; j < nbf; j += FB_THREADS) hist[j] = 0;
  __syncthreads();
  const int* dch = dst + e0;
  const int* sch = src + e0;
  const int nv = lim >> 2;
  for (int k = tid; k < nv; k += FB_THREADS) {
    int4 d = reinterpret_cast<const int4*>(dch)[k];
    atomicAdd(&hist[d.x >> 8], 1);
    atomicAdd(&hist[d.y >> 8], 1);
    atomicAdd(&hist[d.z >> 8], 1);
    atomicAdd(&hist[d.w >> 8], 1);
  }
  for (int k = (nv << 2) + tid; k < lim; k += FB_THREADS)
    atomicAdd(&hist[dch[k] >> 8], 1);
  __syncthreads();
  for (int j = tid; j < nbf; j += FB_THREADS) {
    int c = hist[j];
    lbase[j] = c ? atomicAdd(&gcur[j], (c + FB_PAD - 1) & ~(FB_PAD - 1)) : 0;
    hist[j] = 0;
  }
  __syncthreads();
  for (int k = tid; k < nv; k += FB_THREADS) {
    int4 d = reinterpret_cast<const int4*>(dch)[k];
    int4 s = reinterpret_cast<const int4*>(sch)[k];
    int b0 = d.x >> 8, b1 = d.y >> 8, b2 = d.z >> 8, b3 = d.w >> 8;
    int r0 = atomicAdd(&hist[b0], 1) + lbase[b0];
    int r1 = atomicAdd(&hist[b1], 1) + lbase[b1];
    int r2 = atomicAdd(&hist[b2], 1) + lbase[b2];
    int r3 = atomicAdd(&hist[b3], 1) + lbase[b3];
    if (r0 < C) payload[(long long)b0 * C + r0] = (s.x << 8) | (d.x & 255);
    if (r1 < C) payload[(long long)b1 * C + r1] = (s.y << 8) | (d.y & 255);
    if (r2 < C) payload[(long long)b2 * C + r2] = (s.z << 8) | (d.z & 255);
    if (r3 < C) payload[(long long)b3 * C + r3] = (s.w << 8) | (d.w & 255);
  }
  for (int k = (nv << 2) + tid; k < lim; k += FB_THREADS) {
    int d = dch[k], s = sch[k];
    int bk = d >> 8;
    int r = atomicAdd(&hist[bk], 1) + lbase[bk];
    if (r < C) payload[(long long)bk * C + r] = (s << 8) | (d & 255);
  }
  __syncthreads();
  for (int j = tid; j < nbf; j += FB_THREADS) {
    int c = hist[j];
    if (c) {
      int pc = (c + FB_PAD - 1) & ~(FB_PAD - 1);
      long long base = (long long)j * C;
      for (int k = lbase[j] + c; k < lbase[j] + pc; ++k)
        if (k < C) payload[base + k] = -1;
    }
  }
}

// ---------------- per-bucket counting sort to node order -------------------
__global__ __launch_bounds__(256) void k_sort(
    int* __restrict__ payload, const int* __restrict__ gcur, int C,
    int n, const float* __restrict__ x,
    int* __restrict__ off_g, float* __restrict__ y) {
  __shared__ int stage[SORT_STAGE];
  __shared__ int hist[256];
  __shared__ int sbuf[2][256];
  __shared__ int cur[256];
  const int b = blockIdx.x, t = threadIdx.x;
  hist[t] = 0;
  __syncthreads();
  int* seg = payload + (long long)b * C;
  const int L = min(gcur[b], C);
  const int nv = L >> 2;
#pragma unroll 2
  for (int k = t; k < nv; k += 256) {
    int4 p = reinterpret_cast<const int4*>(seg)[k];
    reinterpret_cast<int4*>(stage)[k] = p;
    if (p.x >= 0) atomicAdd(&hist[p.x & 255], 1);
    if (p.y >= 0) atomicAdd(&hist[p.y & 255], 1);
    if (p.z >= 0) atomicAdd(&hist[p.z & 255], 1);
    if (p.w >= 0) atomicAdd(&hist[p.w & 255], 1);
  }
  for (int k = (nv << 2) + t; k < L; k += 256) {
    int p = seg[k];
    stage[k] = p;
    if (p >= 0) atomicAdd(&hist[p & 255], 1);
  }
  __syncthreads();
  sbuf[0][t] = hist[t];
  __syncthreads();
  int pi = 0;
  for (int d = 1; d < 256; d <<= 1) {
    int v = sbuf[pi][t];
    if (t >= d) v += sbuf[pi][t - d];
    sbuf[pi ^ 1][t] = v;
    pi ^= 1;
    __syncthreads();
  }
  const int inc = sbuf[pi][t];
  const int exc = inc - hist[t];
  cur[t] = exc;
  off_g[b * 257 + t] = exc;
  if (t == 255) off_g[b * 257 + 256] = inc;
  const int i = (b << 8) + t;
  if (i < n) y[i] = rsqrtf((float)(hist[t] + 1)) * x[i];
  __syncthreads();
#pragma unroll 4
  for (int k = t; k < L; k += 256) {
    int p = stage[k];
    if (p >= 0) {
      int pos = atomicAdd(&cur[p & 255], 1);
      seg[pos] = p;
    }
  }
}

// ---------------- layer-1 segmented sum -> per-node message g --------------
// g[j] = dinv_j * W2^T relu(W1 * s_j + b1), s_j = dinv_j*(sum_y + y_j).
// The layer-2 per-edge message is exactly g[src]; MLP hoisted here (1 eval
// per NODE instead of per EDGE).
__global__ __launch_bounds__(256) void k_reduce1(
    const int* __restrict__ payload, const int* __restrict__ off_g, int C,
    int n, const float* __restrict__ y,
    const float* __restrict__ W1, const float* __restrict__ b1,
    const float* __restrict__ W2, float4* __restrict__ g) {
  __shared__ float S[256];
  const int b = blockIdx.x, t = threadIdx.x;
  S[t] = 0.0f;
  __syncthreads();
  const int L = off_g[b * 257 + 256];
  const int* seg = payload + (long long)b * C;
  const int lane = t & 63;
  for (int base = t - lane; base < L; base += 256) {
    int k = base + lane;
    bool valid = k < L;
    int p = 0;
    if (valid) p = __builtin_nontemporal_load(seg + k);
    int m = valid ? (p & 255) : 999;
    float v = valid ? y[p >> 8] : 0.0f;
    seg_scan1(m, v);  // DPP segmented scan (VALU pipe)
    int mn = __shfl_down(m, 1, 64);
    if ((lane == 63 || mn != m) && m < 256) atomicAdd(&S[m], v);
  }
  __syncthreads();
  const int i = (b << 8) + t;
  if (i < n) {
    const int deg = off_g[b * 257 + t + 1] - off_g[b * 257 + t];
    const float r = rsqrtf((float)(deg + 1));
    const float s = r * (S[t] + y[i]);
    const float h0 = fmaxf(fmaf(s, W1[0], b1[0]), 0.f);
    const float h1 = fmaxf(fmaf(s, W1[1], b1[1]), 0.f);
    const float h2 = fmaxf(fmaf(s, W1[2], b1[2]), 0.f);
    const float h3 = fmaxf(fmaf(s, W1[3], b1[3]), 0.f);
    g[i] = make_float4(
        r * (h0 * W2[0] + h1 * W2[4] + h2 * W2[8]  + h3 * W2[12]),
        r * (h0 * W2[1] + h1 * W2[5] + h2 * W2[9]  + h3 * W2[13]),
        r * (h0 * W2[2] + h1 * W2[6] + h2 * W2[10] + h3 * W2[14]),
        r * (h0 * W2[3] + h1 * W2[7] + h2 * W2[11] + h3 * W2[15]));
  }
}

// ---------------- layer-2: gather g[src], segmented sum, no MLP ------------
__global__ __launch_bounds__(256) void k_reduce2g(
    const int* __restrict__ payload, const int* __restrict__ off_g, int C,
    int n, const float4* __restrict__ g, const float* __restrict__ b2,
    float4* __restrict__ out) {
  __shared__ float S0[256], S1[256], S2[256], S3[256];
  const int b = blockIdx.x, t = threadIdx.x;
  S0[t] = 0.f; S1[t] = 0.f; S2[t] = 0.f; S3[t] = 0.f;
  __syncthreads();
  const int L = off_g[b * 257 + 256];
  const int* seg = payload + (long long)b * C;
  const int lane = t & 63;
  for (int base = t - lane; base < L; base += 256) {
    int k = base + lane;
    bool valid = k < L;
    int p = 0;
    if (valid) p = __builtin_nontemporal_load(seg + k);
    int m = valid ? (p & 255) : 999;
    float gx = 0.f, gy = 0.f, gz = 0.f, gw = 0.f;
    if (valid) {
      const float4 gv = g[p >> 8];
      gx = gv.x; gy = gv.y; gz = gv.z; gw = gv.w;
    }
    seg_scan4(m, gx, gy, gz, gw);  // DPP segmented scan (VALU pipe)
    int mn = __shfl_down(m, 1, 64);
    if ((lane == 63 || mn != m) && m < 256) {
      atomicAdd(&S0[m], gx);
      atomicAdd(&S1[m], gy);
      atomicAdd(&S2[m], gz);
      atomicAdd(&S3[m], gw);
    }
  }
  __syncthreads();
  const int i = (b << 8) + t;
  if (i < n) {
    const int deg = off_g[b * 257 + t + 1] - off_g[b * 257 + t];
    const float r = rsqrtf((float)(deg + 1));
    const float4 gi = g[i];
    out[i] = make_float4(b2[0] + r * (S0[t] + gi.x),
                         b2[1] + r * (S1[t] + gi.y),
                         b2[2] + r * (S2[t] + gi.z),
                         b2[3] + r * (S3[t] + gi.w));
  }
}

extern "C" void kernel_launch(void* const* d_in, const int* in_sizes, int n_in,
                              void* d_out, int out_size, void* d_ws, size_t ws_size,
                              hipStream_t stream) {
  const float* x  = (const float*)d_in[0];
  const int*   ei = (const int*)d_in[1];
  const float* W1 = (const float*)d_in[2];
  const float* b1 = (const float*)d_in[3];
  const float* W2 = (const float*)d_in[4];
  const float* b2 = (const float*)d_in[5];

  const int n = in_sizes[0];
  const int E = in_sizes[1] / 2;
  const int* src = ei;
  const int* dst = ei + E;

  const int nbf = (n + 255) >> 8;    // fine buckets (256 nodes)
  const int nb1 = (n + 2047) >> 11;  // coarse buckets (2048 nodes)
  auto al = [](size_t v) { return (v + 255) & ~(size_t)255; };

  const size_t nn = (size_t)n;
  size_t sz_off = al((size_t)nbf * 257 * 4);
  size_t sz_y   = al(nn * 4);
  size_t sz_g   = al(nn * 16);
  size_t sz_gc  = al(((size_t)nb1 + nbf) * 4);
  size_t fixed = sz_off + sz_y + sz_g + sz_gc;

  // main-path capacities (exact counts + Poisson slack)
  long long mean1 = (long long)E / (nb1 > 0 ? nb1 : 1);
  long long C1ll = ((mean1 + 2048 + 1024) + 15) & ~15LL;
  long long mean2 = (long long)E / nbf;
  long long C2ll = ((mean2 + 1024) + 15) & ~15LL;
  size_t need_main = fixed + al((size_t)nb1 * C1ll * 4) + al((size_t)nbf * C2ll * 4);
  const bool main_ok = (n <= 524288) && (nb1 <= MAXNB1) && (nbf <= MAXNBF) &&
                       (C2ll <= SORT_STAGE) && (need_main <= ws_size);

  if (main_ok) {
    const int C1 = (int)C1ll, C2 = (int)C2ll;
    char* p = (char*)d_ws;
    int*    pay1  = (int*)p;    p += al((size_t)nb1 * C1 * 4);
    int*    pay2  = (int*)p;    p += al((size_t)nbf * C2 * 4);
    int*    gcur1 = (int*)p;    // nb1 + nbf contiguous
    int*    gcur2 = gcur1 + nb1;
    p += sz_gc;
    int*    off_g = (int*)p;    p += sz_off;
    float*  y     = (float*)p;  p += sz_y;
    float4* g     = (float4*)p; p += sz_g;

    hipMemsetAsync(gcur1, 0, ((size_t)nb1 + nbf) * 4, stream);

    int chunk = (int)(((long long)E + B1_BLOCKS - 1) / B1_BLOCKS);
    chunk = (chunk + 3) & ~3;

    k_bin1<<<B1_BLOCKS, B1_THREADS, 0, stream>>>(src, dst, E, chunk, nb1, C1,
                                                 gcur1, pay1);
    k_bin2<<<nb1 * 2, B2_THREADS, 0, stream>>>(pay1, gcur1, C1, C2, gcur2,
                                               pay2);
    k_sort<<<nbf, 256, 0, stream>>>(pay2, gcur2, C2, n, x, off_g, y);
    k_reduce1<<<nbf, 256, 0, stream>>>(pay2, off_g, C2, n, y, W1, b1, W2, g);
    k_reduce2g<<<nbf, 256, 0, stream>>>(pay2, off_g, C2, n, g, b2,
                                        (float4*)d_out);
    return;
  }

  // ---- fallback: round-5 flat binning into fine buckets ----
  {
    double mean = (double)E / nbf;
    long long Cwant = (long long)(mean * 1.10) +
                      (long long)(FB_BLOCKS * FB_PAD / 2) + 512;
    size_t budget = ws_size > fixed ? ws_size - fixed - 4096 : 0;
    long long Cbud = (long long)(budget / ((size_t)nbf * 4));
    long long Cll = Cwant < Cbud ? Cwant : Cbud;
    if (Cll > SORT_STAGE) Cll = SORT_STAGE;
    int C = (int)(Cll & ~(long long)(FB_PAD - 1));

    char* p = (char*)d_ws;
    int*    pay2  = (int*)p;    p += al((size_t)nbf * C * 4);
    int*    gcur  = (int*)p;    p += sz_gc;
    int*    off_g = (int*)p;    p += sz_off;
    float*  y     = (float*)p;  p += sz_y;
    float4* g     = (float4*)p; p += sz_g;

    hipMemsetAsync(gcur, 0, (size_t)nbf * 4, stream);

    int chunk = (int)(((long long)E + FB_BLOCKS - 1) / FB_BLOCKS);
    chunk = (chunk + 3) & ~3;

    k_bin_flat<<<FB_BLOCKS, FB_THREADS, 0, stream>>>(src, dst, E, chunk, nbf,
                                                     C, gcur, pay2);
    k_sort<<<nbf, 256, 0, stream>>>(pay2, gcur, C, n, x, off_g, y);
    k_reduce1<<<nbf, 256, 0, stream>>>(pay2, off_g, C, n, y, W1, b1, W2, g);
    k_reduce2g<<<nbf, 256, 0, stream>>>(pay2, off_g, C, n, g, b2,
                                        (float4*)d_out);
  }
}

// Round 9
// 528.391 us; speedup vs baseline: 1.3346x; 1.0952x over previous
//
#include <hip/hip_runtime.h>

// 2-layer GCNConv, N=500K, E=16M, Cin=1, Cout=4, fp32.
//
// Round-13: exact round-7 champion (bin1 -> bin2 -> sort -> reduce1 ->
// reduce2, DPP-scan reduces, 524us) with ONE change: reduce2 scans
// u = r*relu(W1 s + b1) and applies W2 once per NODE in the epilogue
// (sum_e r*(W2^T h) = W2^T sum_e r*h). Cuts 16 fmaf/edge out of the
// 16M-edge loop while keeping the gathered record at 8B float2 ds --
// round-12 proved a 16B gather record blows per-XCD L2 (4MB) and costs
// 523MB FETCH (+46us). All other kernels byte-identical to champion.

#define B1_BLOCKS 512
#define B1_THREADS 1024
#define TILE1 16384
#define B2_THREADS 1024
#define TILE2 16384
#define MAXNB1 256       // coarse buckets (2048 nodes); needs n <= 524288
#define SORT_STAGE 12032 // ints staged in LDS by k_sort; C2 <= this
// fallback (round-5 flat binning) constants
#define FB_BLOCKS 512
#define FB_THREADS 1024
#define FB_PAD 8
#define MAXNBF 2048

// ---------------- DPP segmented-scan helpers (VALU pipe, no LDS) -----------
template <int CTRL, int RM, int KOLD>
__device__ __forceinline__ void seg_step1(int m, float& a) {
  const int mm = __builtin_amdgcn_update_dpp(KOLD, m, CTRL, RM, 0xf, true);
  const float f = (mm == m) ? 1.0f : 0.0f;
  const float ba = __int_as_float(
      __builtin_amdgcn_update_dpp(0, __float_as_int(a), CTRL, RM, 0xf, true));
  a = fmaf(ba, f, a);
}

template <int CTRL, int RM, int KOLD>
__device__ __forceinline__ void seg_step4(int m, float& gx, float& gy,
                                          float& gz, float& gw) {
  const int mm = __builtin_amdgcn_update_dpp(KOLD, m, CTRL, RM, 0xf, true);
  const float f = (mm == m) ? 1.0f : 0.0f;
  const float bx = __int_as_float(
      __builtin_amdgcn_update_dpp(0, __float_as_int(gx), CTRL, RM, 0xf, true));
  const float by = __int_as_float(
      __builtin_amdgcn_update_dpp(0, __float_as_int(gy), CTRL, RM, 0xf, true));
  const float bz = __int_as_float(
      __builtin_amdgcn_update_dpp(0, __float_as_int(gz), CTRL, RM, 0xf, true));
  const float bw = __int_as_float(
      __builtin_amdgcn_update_dpp(0, __float_as_int(gw), CTRL, RM, 0xf, true));
  gx = fmaf(bx, f, gx);
  gy = fmaf(by, f, gy);
  gz = fmaf(bz, f, gz);
  gw = fmaf(bw, f, gw);
}

__device__ __forceinline__ void seg_scan1(int m, float& a) {
  seg_step1<0x111, 0xf, 0>(m, a);   // row_shr:1
  seg_step1<0x112, 0xf, 0>(m, a);   // row_shr:2
  seg_step1<0x114, 0xf, 0>(m, a);   // row_shr:4
  seg_step1<0x118, 0xf, 0>(m, a);   // row_shr:8
  seg_step1<0x142, 0xa, -1>(m, a);  // row_bcast15 -> rows 1,3
  seg_step1<0x143, 0xc, -1>(m, a);  // row_bcast31 -> rows 2,3
}

__device__ __forceinline__ void seg_scan4(int m, float& gx, float& gy,
                                          float& gz, float& gw) {
  seg_step4<0x111, 0xf, 0>(m, gx, gy, gz, gw);
  seg_step4<0x112, 0xf, 0>(m, gx, gy, gz, gw);
  seg_step4<0x114, 0xf, 0>(m, gx, gy, gz, gw);
  seg_step4<0x118, 0xf, 0>(m, gx, gy, gz, gw);
  seg_step4<0x142, 0xa, -1>(m, gx, gy, gz, gw);
  seg_step4<0x143, 0xc, -1>(m, gx, gy, gz, gw);
}

// ---------------- pass 1: coarse split (LDS-staged, coalesced flush) -------
__global__ __launch_bounds__(B1_THREADS) void k_bin1(
    const int* __restrict__ src, const int* __restrict__ dst, int E,
    int chunk, int nb1, int C1, int* __restrict__ gcur1,
    int* __restrict__ pay1) {
  __shared__ int out[TILE1];
  __shared__ int hist[MAXNB1], toff[MAXNB1], wcur[MAXNB1], gb[MAXNB1];
  __shared__ int sbuf[2][MAXNB1];
  const int tid = threadIdx.x;
  const long long e0 = (long long)blockIdx.x * chunk;
  long long reml = (long long)E - e0;
  const int lim = reml < 0 ? 0 : (reml < chunk ? (int)reml : chunk);
  const int* dch = dst + e0;
  const int* sch = src + e0;

  for (int tb = 0; tb < lim; tb += TILE1) {
    const int tcnt = min(TILE1, lim - tb);
    const int nv = tcnt >> 2;
    for (int j = tid; j < MAXNB1; j += B1_THREADS) hist[j] = 0;
    __syncthreads();

    // phase A: tile histogram of coarse keys
    const int* dt = dch + tb;
    for (int k = tid; k < nv; k += B1_THREADS) {
      int4 d = reinterpret_cast<const int4*>(dt)[k];
      atomicAdd(&hist[d.x >> 11], 1);
      atomicAdd(&hist[d.y >> 11], 1);
      atomicAdd(&hist[d.z >> 11], 1);
      atomicAdd(&hist[d.w >> 11], 1);
    }
    for (int k = (nv << 2) + tid; k < tcnt; k += B1_THREADS)
      atomicAdd(&hist[dt[k] >> 11], 1);
    __syncthreads();

    // phase B: exclusive scan (256-wide) + exact global range reservation
    if (tid < MAXNB1) sbuf[0][tid] = hist[tid];
    __syncthreads();
    int pi = 0;
    for (int dd = 1; dd < MAXNB1; dd <<= 1) {
      if (tid < MAXNB1) {
        int v = sbuf[pi][tid];
        if (tid >= dd) v += sbuf[pi][tid - dd];
        sbuf[pi ^ 1][tid] = v;
      }
      pi ^= 1;
      __syncthreads();
    }
    if (tid < MAXNB1) {
      int c = hist[tid];
      int exc = sbuf[pi][tid] - c;
      toff[tid] = exc;
      wcur[tid] = exc;
      gb[tid] = c ? atomicAdd(&gcur1[tid], c) : 0;
    }
    __syncthreads();

    // phase C: rank + place packed (src<<11 | dst&2047) into LDS out
    const int* st = sch + tb;
    for (int k = tid; k < nv; k += B1_THREADS) {
      int4 d = reinterpret_cast<const int4*>(dt)[k];
      int4 s = reinterpret_cast<const int4*>(st)[k];
      int r0 = atomicAdd(&wcur[d.x >> 11], 1);
      int r1 = atomicAdd(&wcur[d.y >> 11], 1);
      int r2 = atomicAdd(&wcur[d.z >> 11], 1);
      int r3 = atomicAdd(&wcur[d.w >> 11], 1);
      out[r0] = (s.x << 11) | (d.x & 2047);
      out[r1] = (s.y << 11) | (d.y & 2047);
      out[r2] = (s.z << 11) | (d.z & 2047);
      out[r3] = (s.w << 11) | (d.w & 2047);
    }
    for (int k = (nv << 2) + tid; k < tcnt; k += B1_THREADS) {
      int d = dt[k], s = st[k];
      int r = atomicAdd(&wcur[d >> 11], 1);
      out[r] = (s << 11) | (d & 2047);
    }
    __syncthreads();

    // phase D: wave-per-bucket coalesced copy LDS -> global
    const int wv = tid >> 6, lane = tid & 63;
    for (int j = wv; j < nb1; j += 16) {
      const int c = wcur[j] - toff[j];
      if (!c) continue;
      const int gbase = gb[j];
      const long long pbase = (long long)j * C1;
      for (int q = lane; q < c; q += 64) {
        int gi = gbase + q;
        if (gi < C1) pay1[pbase + gi] = out[toff[j] + q];
      }
    }
    __syncthreads();
  }
}

// ---------------- pass 2: fine split (8 buckets per coarse) ----------------
__global__ __launch_bounds__(B2_THREADS) void k_bin2(
    const int* __restrict__ pay1, const int* __restrict__ gcur1, int C1,
    int C2, int* __restrict__ gcur2, int* __restrict__ pay2) {
  __shared__ int out[TILE2];
  __shared__ int hist[8], toff9[9], wcur[8], gb[8];
  const int cb = blockIdx.x >> 1;
  const int half = blockIdx.x & 1;
  const int tid = threadIdx.x;
  const int Lc = min(gcur1[cb], C1);
  int mid = ((Lc >> 1) + 3) & ~3;
  if (mid > Lc) mid = Lc;
  const int h0 = half ? mid : 0;
  const int h1 = half ? Lc : mid;
  const int* seg = pay1 + (long long)cb * C1;

  for (int tb = h0; tb < h1; tb += TILE2) {
    const int tcnt = min(TILE2, h1 - tb);
    const int nv = tcnt >> 2;
    if (tid < 8) hist[tid] = 0;
    __syncthreads();
    const int* pt = seg + tb;

    for (int k = tid; k < nv; k += B2_THREADS) {
      int4 p = reinterpret_cast<const int4*>(pt)[k];
      atomicAdd(&hist[(p.x >> 8) & 7], 1);
      atomicAdd(&hist[(p.y >> 8) & 7], 1);
      atomicAdd(&hist[(p.z >> 8) & 7], 1);
      atomicAdd(&hist[(p.w >> 8) & 7], 1);
    }
    for (int k = (nv << 2) + tid; k < tcnt; k += B2_THREADS)
      atomicAdd(&hist[(pt[k] >> 8) & 7], 1);
    __syncthreads();

    if (tid == 0) {
      int run = 0;
      for (int j = 0; j < 8; ++j) { toff9[j] = run; run += hist[j]; }
      toff9[8] = run;
    }
    __syncthreads();
    if (tid < 8) {
      wcur[tid] = toff9[tid];
      gb[tid] = hist[tid] ? atomicAdd(&gcur2[cb * 8 + tid], hist[tid]) : 0;
    }
    __syncthreads();

    for (int k = tid; k < nv; k += B2_THREADS) {
      int4 p = reinterpret_cast<const int4*>(pt)[k];
      out[atomicAdd(&wcur[(p.x >> 8) & 7], 1)] = ((p.x >> 11) << 8) | (p.x & 255);
      out[atomicAdd(&wcur[(p.y >> 8) & 7], 1)] = ((p.y >> 11) << 8) | (p.y & 255);
      out[atomicAdd(&wcur[(p.z >> 8) & 7], 1)] = ((p.z >> 11) << 8) | (p.z & 255);
      out[atomicAdd(&wcur[(p.w >> 8) & 7], 1)] = ((p.w >> 11) << 8) | (p.w & 255);
    }
    for (int k = (nv << 2) + tid; k < tcnt; k += B2_THREADS) {
      int p = pt[k];
      out[atomicAdd(&wcur[(p >> 8) & 7], 1)] = ((p >> 11) << 8) | (p & 255);
    }
    __syncthreads();

    const int total = toff9[8];
    for (int q = tid; q < total; q += B2_THREADS) {
      int j = (q >= toff9[4]) ? 4 : 0;
      j += (q >= toff9[j + 2]) ? 2 : 0;
      j += (q >= toff9[j + 1]) ? 1 : 0;
      int o = gb[j] + (q - toff9[j]);
      if (o < C2) pay2[(long long)(cb * 8 + j) * C2 + o] = out[q];
    }
    __syncthreads();
  }
}

// ---------------- fallback flat binning (round-5, proven) ------------------
__global__ __launch_bounds__(FB_THREADS) void k_bin_flat(
    const int* __restrict__ src, const int* __restrict__ dst, int E,
    int chunk, int nbf, int C, int* __restrict__ gcur,
    int* __restrict__ payload) {
  __shared__ int hist[MAXNBF];
  __shared__ int lbase[MAXNBF];
  const int tid = threadIdx.x;
  const long long e0 = (long long)blockIdx.x * chunk;
  long long rem = (long long)E - e0;
  int lim = rem < 0 ? 0 : (rem < chunk ? (int)rem : chunk);
  for (int j = tid; j < nbf; j += FB_THREADS) hist[j] = 0;
  __syncthreads();
  const int* dch = dst + e0;
  const int* sch = src + e0;
  const int nv = lim >> 2;
  for (int k = tid; k < nv; k += FB_THREADS) {
    int4 d = reinterpret_cast<const int4*>(dch)[k];
    atomicAdd(&hist[d.x >> 8], 1);
    atomicAdd(&hist[d.y >> 8], 1);
    atomicAdd(&hist[d.z >> 8], 1);
    atomicAdd(&hist[d.w >> 8], 1);
  }
  for (int k = (nv << 2) + tid; k < lim; k += FB_THREADS)
    atomicAdd(&hist[dch[k] >> 8], 1);
  __syncthreads();
  for (int j = tid; j < nbf; j += FB_THREADS) {
    int c = hist[j];
    lbase[j] = c ? atomicAdd(&gcur[j], (c + FB_PAD - 1) & ~(FB_PAD - 1)) : 0;
    hist[j] = 0;
  }
  __syncthreads();
  for (int k = tid; k < nv; k += FB_THREADS) {
    int4 d = reinterpret_cast<const int4*>(dch)[k];
    int4 s = reinterpret_cast<const int4*>(sch)[k];
    int b0 = d.x >> 8, b1 = d.y >> 8, b2 = d.z >> 8, b3 = d.w >> 8;
    int r0 = atomicAdd(&hist[b0], 1) + lbase[b0];
    int r1 = atomicAdd(&hist[b1], 1) + lbase[b1];
    int r2 = atomicAdd(&hist[b2], 1) + lbase[b2];
    int r3 = atomicAdd(&hist[b3], 1) + lbase[b3];
    if (r0 < C) payload[(long long)b0 * C + r0] = (s.x << 8) | (d.x & 255);
    if (r1 < C) payload[(long long)b1 * C + r1] = (s.y << 8) | (d.y & 255);
    if (r2 < C) payload[(long long)b2 * C + r2] = (s.z << 8) | (d.z & 255);
    if (r3 < C) payload[(long long)b3 * C + r3] = (s.w << 8) | (d.w & 255);
  }
  for (int k = (nv << 2) + tid; k < lim; k += FB_THREADS) {
    int d = dch[k], s = sch[k];
    int bk = d >> 8;
    int r = atomicAdd(&hist[bk], 1) + lbase[bk];
    if (r < C) payload[(long long)bk * C + r] = (s << 8) | (d & 255);
  }
  __syncthreads();
  for (int j = tid; j < nbf; j += FB_THREADS) {
    int c = hist[j];
    if (c) {
      int pc = (c + FB_PAD - 1) & ~(FB_PAD - 1);
      long long base = (long long)j * C;
      for (int k = lbase[j] + c; k < lbase[j] + pc; ++k)
        if (k < C) payload[base + k] = -1;
    }
  }
}

// ---------------- per-bucket counting sort to node order -------------------
__global__ __launch_bounds__(256) void k_sort(
    int* __restrict__ payload, const int* __restrict__ gcur, int C,
    int n, const float* __restrict__ x,
    int* __restrict__ off_g, float* __restrict__ y) {
  __shared__ int stage[SORT_STAGE];
  __shared__ int hist[256];
  __shared__ int sbuf[2][256];
  __shared__ int cur[256];
  const int b = blockIdx.x, t = threadIdx.x;
  hist[t] = 0;
  __syncthreads();
  int* seg = payload + (long long)b * C;
  const int L = min(gcur[b], C);
  const int nv = L >> 2;
#pragma unroll 2
  for (int k = t; k < nv; k += 256) {
    int4 p = reinterpret_cast<const int4*>(seg)[k];
    reinterpret_cast<int4*>(stage)[k] = p;
    if (p.x >= 0) atomicAdd(&hist[p.x & 255], 1);
    if (p.y >= 0) atomicAdd(&hist[p.y & 255], 1);
    if (p.z >= 0) atomicAdd(&hist[p.z & 255], 1);
    if (p.w >= 0) atomicAdd(&hist[p.w & 255], 1);
  }
  for (int k = (nv << 2) + t; k < L; k += 256) {
    int p = seg[k];
    stage[k] = p;
    if (p >= 0) atomicAdd(&hist[p & 255], 1);
  }
  __syncthreads();
  sbuf[0][t] = hist[t];
  __syncthreads();
  int pi = 0;
  for (int d = 1; d < 256; d <<= 1) {
    int v = sbuf[pi][t];
    if (t >= d) v += sbuf[pi][t - d];
    sbuf[pi ^ 1][t] = v;
    pi ^= 1;
    __syncthreads();
  }
  const int inc = sbuf[pi][t];
  const int exc = inc - hist[t];
  cur[t] = exc;
  off_g[b * 257 + t] = exc;
  if (t == 255) off_g[b * 257 + 256] = inc;
  const int i = (b << 8) + t;
  if (i < n) y[i] = rsqrtf((float)(hist[t] + 1)) * x[i];
  __syncthreads();
#pragma unroll 4
  for (int k = t; k < L; k += 256) {
    int p = stage[k];
    if (p >= 0) {
      int pos = atomicAdd(&cur[p & 255], 1);
      seg[pos] = p;
    }
  }
}

// ---------------- layer-1 segmented sum -> ds = (dinv, s) ------------------
__global__ __launch_bounds__(256) void k_reduce1(
    const int* __restrict__ payload, const int* __restrict__ off_g, int C,
    int n, const float* __restrict__ y, float2* __restrict__ ds) {
  __shared__ float S[256];
  const int b = blockIdx.x, t = threadIdx.x;
  S[t] = 0.0f;
  __syncthreads();
  const int L = off_g[b * 257 + 256];
  const int* seg = payload + (long long)b * C;
  const int lane = t & 63;
  for (int base = t - lane; base < L; base += 256) {
    int k = base + lane;
    bool valid = k < L;
    int p = 0;
    if (valid) p = __builtin_nontemporal_load(seg + k);
    int m = valid ? (p & 255) : 999;
    float v = valid ? y[p >> 8] : 0.0f;
    seg_scan1(m, v);  // DPP segmented scan (VALU pipe)
    int mn = __shfl_down(m, 1, 64);
    if ((lane == 63 || mn != m) && m < 256) atomicAdd(&S[m], v);
  }
  __syncthreads();
  const int i = (b << 8) + t;
  if (i < n) {
    int deg = off_g[b * 257 + t + 1] - off_g[b * 257 + t];
    float r = rsqrtf((float)(deg + 1));
    ds[i] = make_float2(r, r * (S[t] + y[i]));
  }
}

// ---------------- layer-2: gather ds, scan u = r*relu(W1 s + b1) -----------
// W2 applied once per NODE in the epilogue: sum_e r*(W2^T h) = W2^T sum(r*h).
__global__ __launch_bounds__(256) void k_reduce2(
    const int* __restrict__ payload, const int* __restrict__ off_g, int C,
    int n, const float2* __restrict__ ds,
    const float* __restrict__ W1, const float* __restrict__ b1,
    const float* __restrict__ W2, const float* __restrict__ b2,
    float4* __restrict__ out) {
  __shared__ float S0[256], S1[256], S2[256], S3[256];
  const int b = blockIdx.x, t = threadIdx.x;
  S0[t] = 0.f; S1[t] = 0.f; S2[t] = 0.f; S3[t] = 0.f;
  __syncthreads();
  const float w10 = W1[0], w11 = W1[1], w12 = W1[2], w13 = W1[3];
  const float c10 = b1[0], c11 = b1[1], c12 = b1[2], c13 = b1[3];
  float w2[16];
#pragma unroll
  for (int k = 0; k < 16; ++k) w2[k] = W2[k];

  const int L = off_g[b * 257 + 256];
  const int* seg = payload + (long long)b * C;
  const int lane = t & 63;
  for (int base = t - lane; base < L; base += 256) {
    int k = base + lane;
    bool valid = k < L;
    int p = 0;
    if (valid) p = __builtin_nontemporal_load(seg + k);
    int m = valid ? (p & 255) : 999;
    float2 v = valid ? ds[p >> 8] : make_float2(0.f, 0.f);
    float r = valid ? v.x : 0.0f;  // r=0 zeroes the whole contribution
    float s = v.y;
    // u = r * relu(W1 s + b1)  (4 comps; W2 deferred to epilogue)
    float u0 = r * fmaxf(fmaf(s, w10, c10), 0.f);
    float u1 = r * fmaxf(fmaf(s, w11, c11), 0.f);
    float u2 = r * fmaxf(fmaf(s, w12, c12), 0.f);
    float u3 = r * fmaxf(fmaf(s, w13, c13), 0.f);
    seg_scan4(m, u0, u1, u2, u3);  // DPP segmented scan (VALU pipe)
    int mn = __shfl_down(m, 1, 64);
    if ((lane == 63 || mn != m) && m < 256) {
      atomicAdd(&S0[m], u0);
      atomicAdd(&S1[m], u1);
      atomicAdd(&S2[m], u2);
      atomicAdd(&S3[m], u3);
    }
  }
  __syncthreads();
  const int i = (b << 8) + t;
  if (i < n) {
    const float2 v = ds[i];
    const float r = v.x, s = v.y;
    // self-loop term joins the pre-W2 sum: T = sum_edges(r h) + r*h_self
    const float T0 = S0[t] + r * fmaxf(fmaf(s, w10, c10), 0.f);
    const float T1 = S1[t] + r * fmaxf(fmaf(s, w11, c11), 0.f);
    const float T2 = S2[t] + r * fmaxf(fmaf(s, w12, c12), 0.f);
    const float T3 = S3[t] + r * fmaxf(fmaf(s, w13, c13), 0.f);
    out[i] = make_float4(
        b2[0] + r * (T0 * w2[0] + T1 * w2[4] + T2 * w2[8]  + T3 * w2[12]),
        b2[1] + r * (T0 * w2[1] + T1 * w2[5] + T2 * w2[9]  + T3 * w2[13]),
        b2[2] + r * (T0 * w2[2] + T1 * w2[6] + T2 * w2[10] + T3 * w2[14]),
        b2[3] + r * (T0 * w2[3] + T1 * w2[7] + T2 * w2[11] + T3 * w2[15]));
  }
}

extern "C" void kernel_launch(void* const* d_in, const int* in_sizes, int n_in,
                              void* d_out, int out_size, void* d_ws, size_t ws_size,
                              hipStream_t stream) {
  const float* x  = (const float*)d_in[0];
  const int*   ei = (const int*)d_in[1];
  const float* W1 = (const float*)d_in[2];
  const float* b1 = (const float*)d_in[3];
  const float* W2 = (const float*)d_in[4];
  const float* b2 = (const float*)d_in[5];

  const int n = in_sizes[0];
  const int E = in_sizes[1] / 2;
  const int* src = ei;
  const int* dst = ei + E;

  const int nbf = (n + 255) >> 8;    // fine buckets (256 nodes)
  const int nb1 = (n + 2047) >> 11;  // coarse buckets (2048 nodes)
  auto al = [](size_t v) { return (v + 255) & ~(size_t)255; };

  const size_t nn = (size_t)n;
  size_t sz_off = al((size_t)nbf * 257 * 4);
  size_t sz_y   = al(nn * 4);
  size_t sz_ds  = al(nn * 8);
  size_t sz_gc  = al(((size_t)nb1 + nbf) * 4);
  size_t fixed = sz_off + sz_y + sz_ds + sz_gc;

  // main-path capacities (exact counts + Poisson slack)
  long long mean1 = (long long)E / (nb1 > 0 ? nb1 : 1);
  long long C1ll = ((mean1 + 2048 + 1024) + 15) & ~15LL;
  long long mean2 = (long long)E / nbf;
  long long C2ll = ((mean2 + 1024) + 15) & ~15LL;
  size_t need_main = fixed + al((size_t)nb1 * C1ll * 4) + al((size_t)nbf * C2ll * 4);
  const bool main_ok = (n <= 524288) && (nb1 <= MAXNB1) && (nbf <= MAXNBF) &&
                       (C2ll <= SORT_STAGE) && (need_main <= ws_size);

  if (main_ok) {
    const int C1 = (int)C1ll, C2 = (int)C2ll;
    char* p = (char*)d_ws;
    int*    pay1  = (int*)p;    p += al((size_t)nb1 * C1 * 4);
    int*    pay2  = (int*)p;    p += al((size_t)nbf * C2 * 4);
    int*    gcur1 = (int*)p;    // nb1 + nbf contiguous
    int*    gcur2 = gcur1 + nb1;
    p += sz_gc;
    int*    off_g = (int*)p;    p += sz_off;
    float*  y     = (float*)p;  p += sz_y;
    float2* ds    = (float2*)p; p += sz_ds;

    hipMemsetAsync(gcur1, 0, ((size_t)nb1 + nbf) * 4, stream);

    int chunk = (int)(((long long)E + B1_BLOCKS - 1) / B1_BLOCKS);
    chunk = (chunk + 3) & ~3;

    k_bin1<<<B1_BLOCKS, B1_THREADS, 0, stream>>>(src, dst, E, chunk, nb1, C1,
                                                 gcur1, pay1);
    k_bin2<<<nb1 * 2, B2_THREADS, 0, stream>>>(pay1, gcur1, C1, C2, gcur2,
                                               pay2);
    k_sort<<<nbf, 256, 0, stream>>>(pay2, gcur2, C2, n, x, off_g, y);
    k_reduce1<<<nbf, 256, 0, stream>>>(pay2, off_g, C2, n, y, ds);
    k_reduce2<<<nbf, 256, 0, stream>>>(pay2, off_g, C2, n, ds, W1, b1, W2, b2,
                                       (float4*)d_out);
    return;
  }

  // ---- fallback: round-5 flat binning into fine buckets ----
  {
    double mean = (double)E / nbf;
    long long Cwant = (long long)(mean * 1.10) +
                      (long long)(FB_BLOCKS * FB_PAD / 2) + 512;
    size_t budget = ws_size > fixed ? ws_size - fixed - 4096 : 0;
    long long Cbud = (long long)(budget / ((size_t)nbf * 4));
    long long Cll = Cwant < Cbud ? Cwant : Cbud;
    if (Cll > SORT_STAGE) Cll = SORT_STAGE;
    int C = (int)(Cll & ~(long long)(FB_PAD - 1));

    char* p = (char*)d_ws;
    int*    pay2  = (int*)p;    p += al((size_t)nbf * C * 4);
    int*    gcur  = (int*)p;    p += sz_gc;
    int*    off_g = (int*)p;    p += sz_off;
    float*  y     = (float*)p;  p += sz_y;
    float2* ds    = (float2*)p; p += sz_ds;

    hipMemsetAsync(gcur, 0, (size_t)nbf * 4, stream);

    int chunk = (int)(((long long)E + FB_BLOCKS - 1) / FB_BLOCKS);
    chunk = (chunk + 3) & ~3;

    k_bin_flat<<<FB_BLOCKS, FB_THREADS, 0, stream>>>(src, dst, E, chunk, nbf,
                                                     C, gcur, pay2);
    k_sort<<<nbf, 256, 0, stream>>>(pay2, gcur, C, n, x, off_g, y);
    k_reduce1<<<nbf, 256, 0, stream>>>(pay2, off_g, C, n, y, ds);
    k_reduce2<<<nbf, 256, 0, stream>>>(pay2, off_g, C, n, ds, W1, b1, W2, b2,
                                       (float4*)d_out);
  }
}